// Round 8
// baseline (303.295 us; speedup 1.0000x reference)
//
#include <hip/hip_runtime.h>

typedef __attribute__((ext_vector_type(8))) short short8;   // 8 bf16 (4 VGPR)
typedef __attribute__((ext_vector_type(4))) float f32x4;    // MFMA acc

static const int NU = 100000;
static const int NM = 20000;
static const int NE = 600000;
static const int FEAT = 64;
static const int HID = 128;
static const int OUTD = 64;
static const int NTOT = NU + NM;
static const int NLIST = 2 * NE;
static const int CVT_TOT = 81920 + NM * FEAT;   // weights + movie_x

// bucket geometry: users 512 nodes/bucket, movies 128 nodes/bucket
static const int UB_SHIFT = 9;
static const int MB_SHIFT = 7;
static const int NBU = (NU + 511) >> 9;           // 196
static const int NBM = (NM + 127) >> 7;           // 157
static const int NBUCK = NBU + NBM;               // 353
static const int EPB = 4096;
static const int NPBLK = (NE + EPB - 1) / EPB;    // 147

__device__ inline float b2f(unsigned short h) {
    unsigned int u = ((unsigned int)h) << 16;
    float f; __builtin_memcpy(&f, &u, 4); return f;
}
__device__ inline unsigned short f2b(float f) {
    unsigned int u; __builtin_memcpy(&u, &f, 4);
    u += 0x7FFFu + ((u >> 16) & 1u);            // RNE
    return (unsigned short)(u >> 16);
}
__device__ inline unsigned int pk2(float a, float b) {
    return (unsigned int)f2b(a) | ((unsigned int)f2b(b) << 16);
}
// XOR swizzle within a row: spreads 16B frag slots across banks (G4)
__device__ inline int wswz(int row, int bc, int rowbytes) {
    return row * rowbytes + (bc ^ ((row & 7) << 4));
}

// ---------------- CSR build (hist -> scan -> partition -> per-bucket CSR) ----------------
__global__ __launch_bounds__(256) void k_hist(const int* __restrict__ ui,
                                              const int* __restrict__ mi,
                                              int* __restrict__ ghist) {
    __shared__ int h[NBUCK];
    const int tid = threadIdx.x;
    for (int i = tid; i < NBUCK; i += 256) h[i] = 0;
    __syncthreads();
#pragma unroll
    for (int it = 0; it < EPB / 256; ++it) {
        int e = blockIdx.x * EPB + it * 256 + tid;
        if (e < NE) {
            atomicAdd(&h[ui[e] >> UB_SHIFT], 1);
            atomicAdd(&h[NBU + (mi[e] >> MB_SHIFT)], 1);
        }
    }
    __syncthreads();
    for (int i = tid; i < NBUCK; i += 256)
        if (h[i]) atomicAdd(&ghist[i], h[i]);
}

__global__ __launch_bounds__(512) void k_bscan(const int* __restrict__ ghist,
                                               int* __restrict__ bb,
                                               int* __restrict__ gcur) {
    __shared__ int s[512];
    const int tid = threadIdx.x;
    int v = (tid < NBUCK) ? ghist[tid] : 0;
    s[tid] = v;
    __syncthreads();
#pragma unroll
    for (int off = 1; off < 512; off <<= 1) {
        int x = (tid >= off) ? s[tid - off] : 0;
        __syncthreads();
        s[tid] += x;
        __syncthreads();
    }
    int excl = s[tid] - v;
    if (tid < NBUCK) { bb[tid] = excl; gcur[tid] = excl; }
    if (tid == 511) bb[NBUCK] = s[511];
}

__global__ __launch_bounds__(256) void k_part(const int* __restrict__ ui,
                                              const int* __restrict__ mi,
                                              int* __restrict__ gcur,
                                              int* __restrict__ entries) {
    __shared__ int h[NBUCK], base[NBUCK], cur[NBUCK];
    const int tid = threadIdx.x;
    for (int i = tid; i < NBUCK; i += 256) h[i] = 0;
    __syncthreads();

    int eu[EPB / 256], em[EPB / 256];
#pragma unroll
    for (int it = 0; it < EPB / 256; ++it) {
        int e = blockIdx.x * EPB + it * 256 + tid;
        if (e < NE) {
            eu[it] = ui[e]; em[it] = mi[e];
            atomicAdd(&h[eu[it] >> UB_SHIFT], 1);
            atomicAdd(&h[NBU + (em[it] >> MB_SHIFT)], 1);
        } else eu[it] = -1;
    }
    __syncthreads();
    for (int i = tid; i < NBUCK; i += 256) {
        int c = h[i];
        base[i] = c ? atomicAdd(&gcur[i], c) : 0;
        cur[i] = 0;
    }
    __syncthreads();
#pragma unroll
    for (int it = 0; it < EPB / 256; ++it) {
        if (eu[it] < 0) continue;
        int u = eu[it], m = em[it];
        int bu = u >> UB_SHIFT;
        int o1 = base[bu] + atomicAdd(&cur[bu], 1);
        entries[o1] = (m << UB_SHIFT) | (u & 511);
        int bm = NBU + (m >> MB_SHIFT);
        int o2 = base[bm] + atomicAdd(&cur[bm], 1);
        entries[o2] = (u << MB_SHIFT) | (m & 127);
    }
}

__global__ __launch_bounds__(256) void k_csr(const int* __restrict__ bb,
                                             const int* __restrict__ entries,
                                             int* __restrict__ rp,
                                             int* __restrict__ list) {
    __shared__ int lcnt[512], lrp[512], lcur[512], ps[256];
    const int b = blockIdx.x;
    const int tid = threadIdx.x;
    const int s = bb[b], e = bb[b + 1];
    const bool isU = b < NBU;
    const int shift = isU ? UB_SHIFT : MB_SHIFT;
    const int mask = isU ? 511 : 127;
    const int n0 = isU ? (b << UB_SHIFT) : ((b - NBU) << MB_SHIFT);
    const int nNodes = isU ? min(512, NU - n0) : min(128, NM - n0);
    const int g0 = isU ? n0 : NU + n0;

    for (int i = tid; i < 512; i += 256) { lcnt[i] = 0; lcur[i] = 0; }
    __syncthreads();
    for (int i = s + tid; i < e; i += 256)
        atomicAdd(&lcnt[entries[i] & mask], 1);
    __syncthreads();
    int a0 = lcnt[2 * tid], a1 = lcnt[2 * tid + 1];
    int pr = a0 + a1;
    ps[tid] = pr;
    __syncthreads();
#pragma unroll
    for (int off = 1; off < 256; off <<= 1) {
        int x = (tid >= off) ? ps[tid - off] : 0;
        __syncthreads();
        ps[tid] += x;
        __syncthreads();
    }
    int excl = ps[tid] - pr;
    lrp[2 * tid] = excl;
    lrp[2 * tid + 1] = excl + a0;
    __syncthreads();
    for (int i = tid; i < nNodes; i += 256) rp[g0 + i] = s + lrp[i];
    if (b == NBUCK - 1 && tid == 0) rp[NTOT] = e;
    for (int i = s + tid; i < e; i += 256) {
        int p = entries[i];
        int dl = p & mask;
        int off = s + lrp[dl] + atomicAdd(&lcur[dl], 1);
        list[off] = p >> shift;
    }
}

// ---------------- fp32 -> bf16 conversion (weights + movie_x) ----------------
__global__ void k_cvt(const float* __restrict__ w1l, const float* __restrict__ w2l,
                      const float* __restrict__ w2r, const float* __restrict__ w3l,
                      const float* __restrict__ w3r, const float* __restrict__ wl1,
                      const float* __restrict__ wl2, const float* __restrict__ mx,
                      unsigned short* __restrict__ dst) {
    int g = blockIdx.x * blockDim.x + threadIdx.x;
    if (g >= CVT_TOT) return;
    const float* s; int o;
    if      (g < 8192)   { s = w1l; o = g; }
    else if (g < 24576)  { s = w2l; o = g - 8192; }
    else if (g < 32768)  { s = w2r; o = g - 24576; }
    else if (g < 49152)  { s = w3l; o = g - 32768; }
    else if (g < 65536)  { s = w3r; o = g - 49152; }
    else if (g < 73728)  { s = wl1; o = g - 65536; }
    else if (g < 81920)  { s = wl2; o = g - 73728; }
    else                 { s = mx;  o = g - 81920; }
    dst[g] = f2b(s[o]);
}

// ---------------- c1 = b1 + user_emb @ W1r^T ----------------
__global__ void k_c1(const float* __restrict__ ue, const float* __restrict__ w1r,
                     const float* __restrict__ b1, float* __restrict__ c1) {
    int h = threadIdx.x;
    float a = 0.f;
#pragma unroll 16
    for (int k = 0; k < HID; ++k) a += ue[k] * w1r[h * HID + k];
    c1[h] = a + b1[h];
}

// ================= fused conv1: gather(mxb)->LDS mean tile -> GEMM(W1l) -> user_x =================
__global__ __launch_bounds__(256) void k_g1(const unsigned short* __restrict__ mxb,
                                            const int* __restrict__ rp,
                                            const int* __restrict__ list,
                                            const unsigned short* __restrict__ W1l,
                                            const float* __restrict__ c1,
                                            unsigned short* __restrict__ user_x, int M) {
    __shared__ __align__(16) char lds[32768];   // [0,16K) mean tile (128B rows); [16K,32K) W1l
    const int tid = threadIdx.x;
    const int lane = tid & 63;
    const int wv = tid >> 6;
    const int rbase = blockIdx.x * 128 + wv * 32;
    const int lr = lane & 15;
    const int kg = lane >> 4;

    // stage W1l [128][64] bf16 (128B rows)
#pragma unroll
    for (int i = 0; i < 4; ++i) {
        int idx = tid + i * 256;
        int row = idx >> 3, bc = (idx & 7) << 4;
        *reinterpret_cast<uint4*>(lds + 16384 + wswz(row, bc, 128)) =
            *reinterpret_cast<const uint4*>((const char*)W1l + idx * 16);
    }
    // gather 128 rows: 8 lanes per node, 4 iterations
#pragma unroll
    for (int it = 0; it < 4; ++it) {
        int nl = it * 32 + (tid >> 3);
        int node = blockIdx.x * 128 + nl;
        if (node < M) {
            int c8 = (tid & 7) * 8;
            int s = rp[node], e = rp[node + 1];
            float a[8];
#pragma unroll
            for (int j = 0; j < 8; ++j) a[j] = 0.f;
            int i = s;
            for (; i + 1 < e; i += 2) {
                int r0 = list[i], r1 = list[i + 1];
                short8 v0 = *reinterpret_cast<const short8*>(mxb + (size_t)r0 * FEAT + c8);
                short8 v1 = *reinterpret_cast<const short8*>(mxb + (size_t)r1 * FEAT + c8);
#pragma unroll
                for (int j = 0; j < 8; ++j)
                    a[j] += b2f((unsigned short)v0[j]) + b2f((unsigned short)v1[j]);
            }
            if (i < e) {
                int r0 = list[i];
                short8 v0 = *reinterpret_cast<const short8*>(mxb + (size_t)r0 * FEAT + c8);
#pragma unroll
                for (int j = 0; j < 8; ++j) a[j] += b2f((unsigned short)v0[j]);
            }
            const float sc = 1.0f / (float)max(e - s, 1);
            uint4 o;
            o.x = pk2(a[0] * sc, a[1] * sc); o.y = pk2(a[2] * sc, a[3] * sc);
            o.z = pk2(a[4] * sc, a[5] * sc); o.w = pk2(a[6] * sc, a[7] * sc);
            *reinterpret_cast<uint4*>(lds + wswz(nl, c8 * 2, 128)) = o;
        }
    }
    __syncthreads();

    // x-frags from LDS mean tile
    short8 xb[2][2];
#pragma unroll
    for (int t = 0; t < 2; ++t) {
        int lrow = wv * 32 + t * 16 + lr;
#pragma unroll
        for (int kt = 0; kt < 2; ++kt)
            xb[t][kt] = *reinterpret_cast<const short8*>(
                lds + wswz(lrow, kt * 64 + kg * 16, 128));
    }

    f32x4 acc[2][8];
#pragma unroll
    for (int t = 0; t < 2; ++t)
#pragma unroll
        for (int c = 0; c < 8; ++c) acc[t][c] = (f32x4){0.f, 0.f, 0.f, 0.f};

#pragma unroll
    for (int cg = 0; cg < 8; ++cg) {
        short8 wf[2];
#pragma unroll
        for (int kt = 0; kt < 2; ++kt)
            wf[kt] = *reinterpret_cast<const short8*>(
                lds + 16384 + wswz(cg * 16 + lr, kt * 64 + kg * 16, 128));
#pragma unroll
        for (int kt = 0; kt < 2; ++kt)
#pragma unroll
            for (int t = 0; t < 2; ++t)
                acc[t][cg] = __builtin_amdgcn_mfma_f32_16x16x32_bf16(
                    wf[kt], xb[t][kt], acc[t][cg], 0, 0, 0);
    }

#pragma unroll
    for (int t = 0; t < 2; ++t) {
        const int u = rbase + t * 16 + lr;
        if (u >= M) continue;
#pragma unroll
        for (int cg = 0; cg < 8; ++cg) {
            const int h0 = cg * 16 + kg * 4;
            float4 vv = *reinterpret_cast<const float4*>(c1 + h0);
            float v0 = fmaxf(acc[t][cg][0] + vv.x, 0.f);
            float v1 = fmaxf(acc[t][cg][1] + vv.y, 0.f);
            float v2 = fmaxf(acc[t][cg][2] + vv.z, 0.f);
            float v3 = fmaxf(acc[t][cg][3] + vv.w, 0.f);
            uint2 o = make_uint2(pk2(v0, v1), pk2(v2, v3));
            *reinterpret_cast<uint2*>(user_x + (size_t)u * HID + h0) = o;
        }
    }
}

// ================= fused movie chain: gather(user_x) + GEMM1(W2l,W2r) + GEMM2(Wlin2) =================
// A=[0,32K) mean2 tile -> Z; B=[32K,48K) W2l halves -> Wlin2; C=[48K,64K) W2r full
__global__ __launch_bounds__(256) void k_g2m(
        const unsigned short* __restrict__ user_x, const int* __restrict__ rp,
        const int* __restrict__ list, const unsigned short* __restrict__ mxb,
        const unsigned short* __restrict__ W2l, const unsigned short* __restrict__ W2r,
        const float* __restrict__ b2, unsigned short* __restrict__ movie_z,
        const unsigned short* __restrict__ Wl2, const float* __restrict__ bl2,
        float* __restrict__ out, int M) {
    __shared__ __align__(16) char lds[65536];
    const int tid = threadIdx.x;
    const int lane = tid & 63;
    const int wv = tid >> 6;
    const int rbase = blockIdx.x * 128 + wv * 32;
    const int lr = lane & 15;
    const int kg = lane >> 4;

    // stage W2r full [128][64] (128B rows) -> C ; W2l rows 0..63 (256B rows) -> B
#pragma unroll
    for (int i = 0; i < 4; ++i) {
        int idx = tid + i * 256;
        int row = idx >> 3, bc = (idx & 7) << 4;
        *reinterpret_cast<uint4*>(lds + 49152 + wswz(row, bc, 128)) =
            *reinterpret_cast<const uint4*>((const char*)W2r + idx * 16);
        int row2 = idx >> 4, bc2 = (idx & 15) << 4;
        *reinterpret_cast<uint4*>(lds + 32768 + wswz(row2, bc2, 256)) =
            *reinterpret_cast<const uint4*>((const char*)W2l + idx * 16);
    }
    // xc frags from mxb (movie features, K=64)
    short8 xc[2][2];
#pragma unroll
    for (int t = 0; t < 2; ++t) {
        int row = min(rbase + t * 16 + lr, M - 1);
#pragma unroll
        for (int kt = 0; kt < 2; ++kt)
            xc[t][kt] = *reinterpret_cast<const short8*>(
                mxb + (size_t)row * FEAT + kt * 32 + kg * 8);
    }
    // gather mean2 (16 lanes/node, 8 its) -> A
#pragma unroll
    for (int it = 0; it < 8; ++it) {
        int nl = it * 16 + (tid >> 4);
        int node = blockIdx.x * 128 + nl;
        if (node < M) {
            int c8 = (tid & 15) * 8;
            int g = NU + node;
            int s = rp[g], e = rp[g + 1];
            float a[8];
#pragma unroll
            for (int j = 0; j < 8; ++j) a[j] = 0.f;
            int i = s;
            for (; i + 1 < e; i += 2) {
                int r0 = list[i], r1 = list[i + 1];
                short8 v0 = *reinterpret_cast<const short8*>(user_x + (size_t)r0 * HID + c8);
                short8 v1 = *reinterpret_cast<const short8*>(user_x + (size_t)r1 * HID + c8);
#pragma unroll
                for (int j = 0; j < 8; ++j)
                    a[j] += b2f((unsigned short)v0[j]) + b2f((unsigned short)v1[j]);
            }
            if (i < e) {
                int r0 = list[i];
                short8 v0 = *reinterpret_cast<const short8*>(user_x + (size_t)r0 * HID + c8);
#pragma unroll
                for (int j = 0; j < 8; ++j) a[j] += b2f((unsigned short)v0[j]);
            }
            const float sc = 1.0f / (float)max(e - s, 1);
            uint4 o;
            o.x = pk2(a[0] * sc, a[1] * sc); o.y = pk2(a[2] * sc, a[3] * sc);
            o.z = pk2(a[4] * sc, a[5] * sc); o.w = pk2(a[6] * sc, a[7] * sc);
            *reinterpret_cast<uint4*>(lds + wswz(nl, c8 * 2, 256)) = o;
        }
    }
    __syncthreads();

    // xa frags from A
    short8 xa[2][4];
#pragma unroll
    for (int t = 0; t < 2; ++t) {
        int lrow = wv * 32 + t * 16 + lr;
#pragma unroll
        for (int kt = 0; kt < 4; ++kt)
            xa[t][kt] = *reinterpret_cast<const short8*>(
                lds + wswz(lrow, kt * 64 + kg * 16, 256));
    }

    f32x4 acc[2][8];
#pragma unroll
    for (int t = 0; t < 2; ++t)
#pragma unroll
        for (int c = 0; c < 8; ++c) acc[t][c] = (f32x4){0.f, 0.f, 0.f, 0.f};

    // GEMM1 in two halves over W2l
#pragma unroll
    for (int q = 0; q < 2; ++q) {
        if (q == 1) {
            __syncthreads();
#pragma unroll
            for (int i = 0; i < 4; ++i) {
                int idx = tid + i * 256;
                int row = idx >> 4, bc = (idx & 15) << 4;
                *reinterpret_cast<uint4*>(lds + 32768 + wswz(row, bc, 256)) =
                    *reinterpret_cast<const uint4*>((const char*)W2l + 16384 + idx * 16);
            }
            __syncthreads();
        }
#pragma unroll
        for (int c = 0; c < 4; ++c) {
            const int cg = q * 4 + c;
            short8 wl[4], wr[2];
#pragma unroll
            for (int kt = 0; kt < 4; ++kt)
                wl[kt] = *reinterpret_cast<const short8*>(
                    lds + 32768 + wswz(c * 16 + lr, kt * 64 + kg * 16, 256));
#pragma unroll
            for (int kt = 0; kt < 2; ++kt)
                wr[kt] = *reinterpret_cast<const short8*>(
                    lds + 49152 + wswz(cg * 16 + lr, kt * 64 + kg * 16, 128));
#pragma unroll
            for (int kt = 0; kt < 4; ++kt)
#pragma unroll
                for (int t = 0; t < 2; ++t)
                    acc[t][cg] = __builtin_amdgcn_mfma_f32_16x16x32_bf16(
                        wl[kt], xa[t][kt], acc[t][cg], 0, 0, 0);
#pragma unroll
            for (int kt = 0; kt < 2; ++kt)
#pragma unroll
                for (int t = 0; t < 2; ++t)
                    acc[t][cg] = __builtin_amdgcn_mfma_f32_16x16x32_bf16(
                        wr[kt], xc[t][kt], acc[t][cg], 0, 0, 0);
        }
    }
    __syncthreads();

    // stage Wlin2 -> B; epilogue Z -> A + movie_z
#pragma unroll
    for (int i = 0; i < 4; ++i) {
        int idx = tid + i * 256;
        int row = idx >> 4, bc = (idx & 15) << 4;
        *reinterpret_cast<uint4*>(lds + 32768 + wswz(row, bc, 256)) =
            *reinterpret_cast<const uint4*>((const char*)Wl2 + idx * 16);
    }
#pragma unroll
    for (int t = 0; t < 2; ++t) {
        const int ul = wv * 32 + t * 16 + lr;
        const int u = rbase + t * 16 + lr;
#pragma unroll
        for (int cg = 0; cg < 8; ++cg) {
            const int h0 = cg * 16 + kg * 4;
            float4 vv = *reinterpret_cast<const float4*>(b2 + h0);
            float v0 = fmaxf(acc[t][cg][0] + vv.x, 0.f);
            float v1 = fmaxf(acc[t][cg][1] + vv.y, 0.f);
            float v2 = fmaxf(acc[t][cg][2] + vv.z, 0.f);
            float v3 = fmaxf(acc[t][cg][3] + vv.w, 0.f);
            uint2 pk = make_uint2(pk2(v0, v1), pk2(v2, v3));
            *reinterpret_cast<uint2*>(lds + wswz(ul, h0 * 2, 256)) = pk;
            if (u < M)
                *reinterpret_cast<uint2*>(movie_z + (size_t)u * HID + h0) = pk;
        }
    }
    __syncthreads();

    // GEMM2: out = Z @ Wlin2^T + blin2
    short8 zb[2][4];
#pragma unroll
    for (int t = 0; t < 2; ++t) {
        const int ul = wv * 32 + t * 16 + lr;
#pragma unroll
        for (int kt = 0; kt < 4; ++kt)
            zb[t][kt] = *reinterpret_cast<const short8*>(
                lds + wswz(ul, kt * 64 + kg * 16, 256));
    }
    f32x4 a2[2][4];
#pragma unroll
    for (int t = 0; t < 2; ++t)
#pragma unroll
        for (int c = 0; c < 4; ++c) a2[t][c] = (f32x4){0.f, 0.f, 0.f, 0.f};
#pragma unroll
    for (int cg = 0; cg < 4; ++cg) {
        short8 wf[4];
#pragma unroll
        for (int kt = 0; kt < 4; ++kt)
            wf[kt] = *reinterpret_cast<const short8*>(
                lds + 32768 + wswz(cg * 16 + lr, kt * 64 + kg * 16, 256));
#pragma unroll
        for (int kt = 0; kt < 4; ++kt)
#pragma unroll
            for (int t = 0; t < 2; ++t)
                a2[t][cg] = __builtin_amdgcn_mfma_f32_16x16x32_bf16(
                    wf[kt], zb[t][kt], a2[t][cg], 0, 0, 0);
    }
#pragma unroll
    for (int t = 0; t < 2; ++t) {
        const int u = rbase + t * 16 + lr;
        if (u >= M) continue;
#pragma unroll
        for (int cg = 0; cg < 4; ++cg) {
            const int o0 = cg * 16 + kg * 4;
            float4 bb = *reinterpret_cast<const float4*>(bl2 + o0);
            float4 o = make_float4(a2[t][cg][0] + bb.x, a2[t][cg][1] + bb.y,
                                   a2[t][cg][2] + bb.z, a2[t][cg][3] + bb.w);
            *reinterpret_cast<float4*>(out + (size_t)u * OUTD + o0) = o;
        }
    }
}

// ================= fused user chain: gather(movie_z) + GEMM1(W3l,W3r) + GEMM2(Wlin1) =================
// A=[0,32K) mean3 tile -> Z; B=[32K,48K) W3l halves -> Wlin1; C=[48K,64K) W3r halves
__global__ __launch_bounds__(256) void k_g3u(
        const unsigned short* __restrict__ movie_z, const int* __restrict__ rp,
        const int* __restrict__ list, const unsigned short* __restrict__ user_x,
        const unsigned short* __restrict__ W3l, const unsigned short* __restrict__ W3r,
        const float* __restrict__ b3, const unsigned short* __restrict__ Wl1,
        const float* __restrict__ bl1, float* __restrict__ out, int M) {
    __shared__ __align__(16) char lds[65536];
    const int tid = threadIdx.x;
    const int lane = tid & 63;
    const int wv = tid >> 6;
    const int rbase = blockIdx.x * 128 + wv * 32;
    const int lr = lane & 15;
    const int kg = lane >> 4;

    // stage W3l rows 0..63 -> B, W3r rows 0..63 -> C (256B rows)
#pragma unroll
    for (int i = 0; i < 4; ++i) {
        int idx = tid + i * 256;
        int row = idx >> 4, bc = (idx & 15) << 4;
        int sw = wswz(row, bc, 256);
        *reinterpret_cast<uint4*>(lds + 32768 + sw) =
            *reinterpret_cast<const uint4*>((const char*)W3l + idx * 16);
        *reinterpret_cast<uint4*>(lds + 49152 + sw) =
            *reinterpret_cast<const uint4*>((const char*)W3r + idx * 16);
    }
    // xc frags from user_x (K=128)
    short8 xc[2][4];
#pragma unroll
    for (int t = 0; t < 2; ++t) {
        int row = min(rbase + t * 16 + lr, M - 1);
#pragma unroll
        for (int kt = 0; kt < 4; ++kt)
            xc[t][kt] = *reinterpret_cast<const short8*>(
                user_x + (size_t)row * HID + kt * 32 + kg * 8);
    }
    // gather mean3 from movie_z (16 lanes/node, 8 its) -> A
#pragma unroll
    for (int it = 0; it < 8; ++it) {
        int nl = it * 16 + (tid >> 4);
        int node = blockIdx.x * 128 + nl;
        if (node < M) {
            int c8 = (tid & 15) * 8;
            int s = rp[node], e = rp[node + 1];
            float a[8];
#pragma unroll
            for (int j = 0; j < 8; ++j) a[j] = 0.f;
            int i = s;
            for (; i + 1 < e; i += 2) {
                int r0 = list[i], r1 = list[i + 1];
                short8 v0 = *reinterpret_cast<const short8*>(movie_z + (size_t)r0 * HID + c8);
                short8 v1 = *reinterpret_cast<const short8*>(movie_z + (size_t)r1 * HID + c8);
#pragma unroll
                for (int j = 0; j < 8; ++j)
                    a[j] += b2f((unsigned short)v0[j]) + b2f((unsigned short)v1[j]);
            }
            if (i < e) {
                int r0 = list[i];
                short8 v0 = *reinterpret_cast<const short8*>(movie_z + (size_t)r0 * HID + c8);
#pragma unroll
                for (int j = 0; j < 8; ++j) a[j] += b2f((unsigned short)v0[j]);
            }
            const float sc = 1.0f / (float)max(e - s, 1);
            uint4 o;
            o.x = pk2(a[0] * sc, a[1] * sc); o.y = pk2(a[2] * sc, a[3] * sc);
            o.z = pk2(a[4] * sc, a[5] * sc); o.w = pk2(a[6] * sc, a[7] * sc);
            *reinterpret_cast<uint4*>(lds + wswz(nl, c8 * 2, 256)) = o;
        }
    }
    __syncthreads();

    // xa frags from A
    short8 xa[2][4];
#pragma unroll
    for (int t = 0; t < 2; ++t) {
        int lrow = wv * 32 + t * 16 + lr;
#pragma unroll
        for (int kt = 0; kt < 4; ++kt)
            xa[t][kt] = *reinterpret_cast<const short8*>(
                lds + wswz(lrow, kt * 64 + kg * 16, 256));
    }

    f32x4 acc[2][8];
#pragma unroll
    for (int t = 0; t < 2; ++t)
#pragma unroll
        for (int c = 0; c < 8; ++c) acc[t][c] = (f32x4){0.f, 0.f, 0.f, 0.f};

#pragma unroll
    for (int q = 0; q < 2; ++q) {
        if (q == 1) {
            __syncthreads();
#pragma unroll
            for (int i = 0; i < 4; ++i) {
                int idx = tid + i * 256;
                int row = idx >> 4, bc = (idx & 15) << 4;
                int sw = wswz(row, bc, 256);
                *reinterpret_cast<uint4*>(lds + 32768 + sw) =
                    *reinterpret_cast<const uint4*>((const char*)W3l + 16384 + idx * 16);
                *reinterpret_cast<uint4*>(lds + 49152 + sw) =
                    *reinterpret_cast<const uint4*>((const char*)W3r + 16384 + idx * 16);
            }
            __syncthreads();
        }
#pragma unroll
        for (int c = 0; c < 4; ++c) {
            const int cg = q * 4 + c;
            short8 wl[4], wr[4];
#pragma unroll
            for (int kt = 0; kt < 4; ++kt) {
                int sw = wswz(c * 16 + lr, kt * 64 + kg * 16, 256);
                wl[kt] = *reinterpret_cast<const short8*>(lds + 32768 + sw);
                wr[kt] = *reinterpret_cast<const short8*>(lds + 49152 + sw);
            }
#pragma unroll
            for (int kt = 0; kt < 4; ++kt)
#pragma unroll
                for (int t = 0; t < 2; ++t) {
                    acc[t][cg] = __builtin_amdgcn_mfma_f32_16x16x32_bf16(
                        wl[kt], xa[t][kt], acc[t][cg], 0, 0, 0);
                    acc[t][cg] = __builtin_amdgcn_mfma_f32_16x16x32_bf16(
                        wr[kt], xc[t][kt], acc[t][cg], 0, 0, 0);
                }
        }
    }
    __syncthreads();

    // stage Wlin1 -> B; epilogue Z -> A
#pragma unroll
    for (int i = 0; i < 4; ++i) {
        int idx = tid + i * 256;
        int row = idx >> 4, bc = (idx & 15) << 4;
        *reinterpret_cast<uint4*>(lds + 32768 + wswz(row, bc, 256)) =
            *reinterpret_cast<const uint4*>((const char*)Wl1 + idx * 16);
    }
#pragma unroll
    for (int t = 0; t < 2; ++t) {
        const int ul = wv * 32 + t * 16 + lr;
#pragma unroll
        for (int cg = 0; cg < 8; ++cg) {
            const int h0 = cg * 16 + kg * 4;
            float4 vv = *reinterpret_cast<const float4*>(b3 + h0);
            float v0 = fmaxf(acc[t][cg][0] + vv.x, 0.f);
            float v1 = fmaxf(acc[t][cg][1] + vv.y, 0.f);
            float v2 = fmaxf(acc[t][cg][2] + vv.z, 0.f);
            float v3 = fmaxf(acc[t][cg][3] + vv.w, 0.f);
            uint2 pk = make_uint2(pk2(v0, v1), pk2(v2, v3));
            *reinterpret_cast<uint2*>(lds + wswz(ul, h0 * 2, 256)) = pk;
        }
    }
    __syncthreads();

    // GEMM2: out = Z @ Wlin1^T + blin1
    short8 zb[2][4];
#pragma unroll
    for (int t = 0; t < 2; ++t) {
        const int ul = wv * 32 + t * 16 + lr;
#pragma unroll
        for (int kt = 0; kt < 4; ++kt)
            zb[t][kt] = *reinterpret_cast<const short8*>(
                lds + wswz(ul, kt * 64 + kg * 16, 256));
    }
    f32x4 a2[2][4];
#pragma unroll
    for (int t = 0; t < 2; ++t)
#pragma unroll
        for (int c = 0; c < 4; ++c) a2[t][c] = (f32x4){0.f, 0.f, 0.f, 0.f};
#pragma unroll
    for (int cg = 0; cg < 4; ++cg) {
        short8 wf[4];
#pragma unroll
        for (int kt = 0; kt < 4; ++kt)
            wf[kt] = *reinterpret_cast<const short8*>(
                lds + 32768 + wswz(cg * 16 + lr, kt * 64 + kg * 16, 256));
#pragma unroll
        for (int kt = 0; kt < 4; ++kt)
#pragma unroll
            for (int t = 0; t < 2; ++t)
                a2[t][cg] = __builtin_amdgcn_mfma_f32_16x16x32_bf16(
                    wf[kt], zb[t][kt], a2[t][cg], 0, 0, 0);
    }
#pragma unroll
    for (int t = 0; t < 2; ++t) {
        const int u = rbase + t * 16 + lr;
        if (u >= M) continue;
#pragma unroll
        for (int cg = 0; cg < 4; ++cg) {
            const int o0 = cg * 16 + kg * 4;
            float4 bb = *reinterpret_cast<const float4*>(bl1 + o0);
            float4 o = make_float4(a2[t][cg][0] + bb.x, a2[t][cg][1] + bb.y,
                                   a2[t][cg][2] + bb.z, a2[t][cg][3] + bb.w);
            *reinterpret_cast<float4*>(out + (size_t)u * OUTD + o0) = o;
        }
    }
}

// ---------------- new_index output ----------------
__global__ void k_index(const int* __restrict__ t, float* __restrict__ o, int n, int nu) {
    int i = blockIdx.x * blockDim.x + threadIdx.x;
    if (i < n) {
        o[i] = (float)t[i];
        o[n + i] = (float)(t[n + i] + nu);
    }
}

extern "C" void kernel_launch(void* const* d_in, const int* in_sizes, int n_in,
                              void* d_out, int out_size, void* d_ws, size_t ws_size,
                              hipStream_t stream) {
    const float* movie_x  = (const float*)d_in[0];
    const int*   user_idx = (const int*)d_in[1];
    const int*   movie_idx= (const int*)d_in[2];
    const int*   tuples   = (const int*)d_in[3];
    const float* user_emb = (const float*)d_in[4];
    const float* W1l = (const float*)d_in[5];
    const float* b1  = (const float*)d_in[6];
    const float* W1r = (const float*)d_in[7];
    const float* W2l = (const float*)d_in[8];
    const float* b2  = (const float*)d_in[9];
    const float* W2r = (const float*)d_in[10];
    const float* W3l = (const float*)d_in[11];
    const float* b3  = (const float*)d_in[12];
    const float* W3r = (const float*)d_in[13];
    const float* Wlin1 = (const float*)d_in[14];
    const float* blin1 = (const float*)d_in[15];
    const float* Wlin2 = (const float*)d_in[16];
    const float* blin2 = (const float*)d_in[17];

    float* out = (float*)d_out;

    // ---- workspace layout ----
    char* p = (char*)d_ws;
    int* ghist = (int*)p;  p += 360 * 4;
    int* bb    = (int*)p;  p += 360 * 4;
    int* gcur  = (int*)p;  p += 360 * 4;
    int* entries = (int*)p; p += (size_t)NLIST * 4;
    int* rp    = (int*)p;  p += (size_t)(NTOT + 8) * 4;
    int* list  = (int*)p;  p += (size_t)NLIST * 4;
    float* c1  = (float*)p; p += 128 * 4;
    unsigned short* wb = (unsigned short*)p; p += (size_t)CVT_TOT * 2;
    unsigned short* W1l_b  = wb;
    unsigned short* W2l_b  = wb + 8192;
    unsigned short* W2r_b  = wb + 24576;
    unsigned short* W3l_b  = wb + 32768;
    unsigned short* W3r_b  = wb + 49152;
    unsigned short* Wlin1_b= wb + 65536;
    unsigned short* Wlin2_b= wb + 73728;
    unsigned short* mxb    = wb + 81920;                              // [NM][64]
    unsigned short* user_x = (unsigned short*)p; p += (size_t)NU * HID * 2;
    unsigned short* movie_z= (unsigned short*)p; p += (size_t)NM * HID * 2;

    // ---- CSR build ----
    hipMemsetAsync(ghist, 0, NBUCK * sizeof(int), stream);
    k_hist<<<NPBLK, 256, 0, stream>>>(user_idx, movie_idx, ghist);
    k_bscan<<<1, 512, 0, stream>>>(ghist, bb, gcur);
    k_part<<<NPBLK, 256, 0, stream>>>(user_idx, movie_idx, gcur, entries);
    k_csr<<<NBUCK, 256, 0, stream>>>(bb, entries, rp, list);

    // ---- conversions + c1 ----
    k_cvt<<<(CVT_TOT + 255) / 256, 256, 0, stream>>>(W1l, W2l, W2r, W3l, W3r,
                                                     Wlin1, Wlin2, movie_x, wb);
    k_c1<<<1, 128, 0, stream>>>(user_emb, W1r, b1, c1);

    // ---- conv1 (fused gather + GEMM) -> user_x ----
    k_g1<<<(NU + 127) / 128, 256, 0, stream>>>(mxb, rp, list, W1l_b, c1, user_x, NU);

    // ---- conv2 + lin2 (fused movie chain) ----
    k_g2m<<<(NM + 127) / 128, 256, 0, stream>>>(
        user_x, rp, list, mxb, W2l_b, W2r_b, b2, movie_z, Wlin2_b, blin2,
        out + (size_t)NU * OUTD, NM);

    // ---- conv3 + lin1 (fused user chain) ----
    k_g3u<<<(NU + 127) / 128, 256, 0, stream>>>(
        movie_z, rp, list, user_x, W3l_b, W3r_b, b3, Wlin1_b, blin1, out, NU);

    // ---- new_index ----
    k_index<<<(100000 + 255) / 256, 256, 0, stream>>>(
        tuples, out + (size_t)(NU + NM) * OUTD, 100000, NU);
}

// Round 9
// 183.231 us; speedup vs baseline: 1.6553x; 1.6553x over previous
//
#include <hip/hip_runtime.h>

typedef __attribute__((ext_vector_type(8))) short short8;   // 8 bf16 (4 VGPR)
typedef __attribute__((ext_vector_type(4))) float f32x4;    // MFMA acc

static const int NU = 100000;
static const int NM = 20000;
static const int NE = 600000;
static const int FEAT = 64;
static const int HID = 128;
static const int OUTD = 64;
static const int NTOT = NU + NM;
static const int NLIST = 2 * NE;
static const int CVT_TOT = 81920 + NM * FEAT;   // weights + movie_x
static const int CVT_BLKS = (CVT_TOT + 255) / 256;
static const int IDX_BLKS = (100000 + 255) / 256;

// bucket geometry: users 512 nodes/bucket, movies 128 nodes/bucket
static const int UB_SHIFT = 9;
static const int MB_SHIFT = 7;
static const int NBU = (NU + 511) >> 9;           // 196
static const int NBM = (NM + 127) >> 7;           // 157
static const int NBUCK = NBU + NBM;               // 353
static const int EPB = 4096;
static const int NPBLK = (NE + EPB - 1) / EPB;    // 147

__device__ inline float b2f(unsigned short h) {
    unsigned int u = ((unsigned int)h) << 16;
    float f; __builtin_memcpy(&f, &u, 4); return f;
}
__device__ inline unsigned short f2b(float f) {
    unsigned int u; __builtin_memcpy(&u, &f, 4);
    u += 0x7FFFu + ((u >> 16) & 1u);            // RNE
    return (unsigned short)(u >> 16);
}
__device__ inline unsigned int pk2(float a, float b) {
    return (unsigned int)f2b(a) | ((unsigned int)f2b(b) << 16);
}
// XOR swizzle within a row: spreads 16B frag slots across banks (G4)
__device__ inline int wswz(int row, int bc, int rowbytes) {
    return row * rowbytes + (bc ^ ((row & 7) << 4));
}

// ---------------- CSR build (hist -> scan -> partition -> per-bucket CSR) ----------------
__global__ __launch_bounds__(256) void k_hist(const int* __restrict__ ui,
                                              const int* __restrict__ mi,
                                              int* __restrict__ ghist) {
    __shared__ int h[NBUCK];
    const int tid = threadIdx.x;
    for (int i = tid; i < NBUCK; i += 256) h[i] = 0;
    __syncthreads();
#pragma unroll
    for (int it = 0; it < EPB / 256; ++it) {
        int e = blockIdx.x * EPB + it * 256 + tid;
        if (e < NE) {
            atomicAdd(&h[ui[e] >> UB_SHIFT], 1);
            atomicAdd(&h[NBU + (mi[e] >> MB_SHIFT)], 1);
        }
    }
    __syncthreads();
    for (int i = tid; i < NBUCK; i += 256)
        if (h[i]) atomicAdd(&ghist[i], h[i]);
}

__global__ __launch_bounds__(512) void k_bscan(const int* __restrict__ ghist,
                                               int* __restrict__ bb,
                                               int* __restrict__ gcur) {
    __shared__ int s[512];
    const int tid = threadIdx.x;
    int v = (tid < NBUCK) ? ghist[tid] : 0;
    s[tid] = v;
    __syncthreads();
#pragma unroll
    for (int off = 1; off < 512; off <<= 1) {
        int x = (tid >= off) ? s[tid - off] : 0;
        __syncthreads();
        s[tid] += x;
        __syncthreads();
    }
    int excl = s[tid] - v;
    if (tid < NBUCK) { bb[tid] = excl; gcur[tid] = excl; }
    if (tid == 511) bb[NBUCK] = s[511];
}

__global__ __launch_bounds__(256) void k_part(const int* __restrict__ ui,
                                              const int* __restrict__ mi,
                                              int* __restrict__ gcur,
                                              int* __restrict__ entries) {
    __shared__ int h[NBUCK], base[NBUCK], cur[NBUCK];
    const int tid = threadIdx.x;
    for (int i = tid; i < NBUCK; i += 256) h[i] = 0;
    __syncthreads();

    int eu[EPB / 256], em[EPB / 256];
#pragma unroll
    for (int it = 0; it < EPB / 256; ++it) {
        int e = blockIdx.x * EPB + it * 256 + tid;
        if (e < NE) {
            eu[it] = ui[e]; em[it] = mi[e];
            atomicAdd(&h[eu[it] >> UB_SHIFT], 1);
            atomicAdd(&h[NBU + (em[it] >> MB_SHIFT)], 1);
        } else eu[it] = -1;
    }
    __syncthreads();
    for (int i = tid; i < NBUCK; i += 256) {
        int c = h[i];
        base[i] = c ? atomicAdd(&gcur[i], c) : 0;
        cur[i] = 0;
    }
    __syncthreads();
#pragma unroll
    for (int it = 0; it < EPB / 256; ++it) {
        if (eu[it] < 0) continue;
        int u = eu[it], m = em[it];
        int bu = u >> UB_SHIFT;
        int o1 = base[bu] + atomicAdd(&cur[bu], 1);
        entries[o1] = (m << UB_SHIFT) | (u & 511);
        int bm = NBU + (m >> MB_SHIFT);
        int o2 = base[bm] + atomicAdd(&cur[bm], 1);
        entries[o2] = (u << MB_SHIFT) | (m & 127);
    }
}

__global__ __launch_bounds__(256) void k_csr(const int* __restrict__ bb,
                                             const int* __restrict__ entries,
                                             int* __restrict__ rp,
                                             int* __restrict__ list) {
    __shared__ int lcnt[512], lrp[512], lcur[512], ps[256];
    const int b = blockIdx.x;
    const int tid = threadIdx.x;
    const int s = bb[b], e = bb[b + 1];
    const bool isU = b < NBU;
    const int shift = isU ? UB_SHIFT : MB_SHIFT;
    const int mask = isU ? 511 : 127;
    const int n0 = isU ? (b << UB_SHIFT) : ((b - NBU) << MB_SHIFT);
    const int nNodes = isU ? min(512, NU - n0) : min(128, NM - n0);
    const int g0 = isU ? n0 : NU + n0;

    for (int i = tid; i < 512; i += 256) { lcnt[i] = 0; lcur[i] = 0; }
    __syncthreads();
    for (int i = s + tid; i < e; i += 256)
        atomicAdd(&lcnt[entries[i] & mask], 1);
    __syncthreads();
    int a0 = lcnt[2 * tid], a1 = lcnt[2 * tid + 1];
    int pr = a0 + a1;
    ps[tid] = pr;
    __syncthreads();
#pragma unroll
    for (int off = 1; off < 256; off <<= 1) {
        int x = (tid >= off) ? ps[tid - off] : 0;
        __syncthreads();
        ps[tid] += x;
        __syncthreads();
    }
    int excl = ps[tid] - pr;
    lrp[2 * tid] = excl;
    lrp[2 * tid + 1] = excl + a0;
    __syncthreads();
    for (int i = tid; i < nNodes; i += 256) rp[g0 + i] = s + lrp[i];
    if (b == NBUCK - 1 && tid == 0) rp[NTOT] = e;
    for (int i = s + tid; i < e; i += 256) {
        int p = entries[i];
        int dl = p & mask;
        int off = s + lrp[dl] + atomicAdd(&lcur[dl], 1);
        list[off] = p >> shift;
    }
}

// ---------------- merged small work: cvt (weights+movie_x) + new_index + c1 ----------------
__global__ void k_misc(const float* __restrict__ w1l, const float* __restrict__ w2l,
                       const float* __restrict__ w2r, const float* __restrict__ w3l,
                       const float* __restrict__ w3r, const float* __restrict__ wl1,
                       const float* __restrict__ wl2, const float* __restrict__ mx,
                       unsigned short* __restrict__ dst,
                       const int* __restrict__ tpl, float* __restrict__ oidx,
                       const float* __restrict__ ue, const float* __restrict__ w1r,
                       const float* __restrict__ b1, float* __restrict__ c1) {
    const int b = blockIdx.x;
    if (b < CVT_BLKS) {
        int g = b * 256 + threadIdx.x;
        if (g >= CVT_TOT) return;
        const float* s; int o;
        if      (g < 8192)   { s = w1l; o = g; }
        else if (g < 24576)  { s = w2l; o = g - 8192; }
        else if (g < 32768)  { s = w2r; o = g - 24576; }
        else if (g < 49152)  { s = w3l; o = g - 32768; }
        else if (g < 65536)  { s = w3r; o = g - 49152; }
        else if (g < 73728)  { s = wl1; o = g - 65536; }
        else if (g < 81920)  { s = wl2; o = g - 73728; }
        else                 { s = mx;  o = g - 81920; }
        dst[g] = f2b(s[o]);
    } else if (b < CVT_BLKS + IDX_BLKS) {
        int i = (b - CVT_BLKS) * 256 + threadIdx.x;
        if (i < 100000) {
            oidx[i] = (float)tpl[i];
            oidx[100000 + i] = (float)(tpl[100000 + i] + NU);
        }
    } else {
        int h = threadIdx.x;
        if (h < HID) {
            float a = 0.f;
#pragma unroll 16
            for (int k = 0; k < HID; ++k) a += ue[k] * w1r[h * HID + k];
            c1[h] = a + b1[h];
        }
    }
}

// ---------------- bf16 gather-based segment mean (high-TLP, standalone) ----------------
template<int C>
__global__ __launch_bounds__(256) void k_gather_b(const unsigned short* __restrict__ src,
                                                  const int* __restrict__ rp,
                                                  const int* __restrict__ list,
                                                  unsigned short* __restrict__ dst,
                                                  int base, int n) {
    constexpr int TPN = C / 8;
    constexpr int NPB = 256 / TPN;
    const int node = blockIdx.x * NPB + threadIdx.x / TPN;
    if (node >= n) return;
    const int c8 = (threadIdx.x % TPN) * 8;
    const int g = base + node;
    const int s = rp[g], e = rp[g + 1];

    float a[8];
#pragma unroll
    for (int j = 0; j < 8; ++j) a[j] = 0.f;

    int i = s;
    for (; i + 1 < e; i += 2) {
        int r0 = list[i], r1 = list[i + 1];
        short8 v0 = *reinterpret_cast<const short8*>(src + (size_t)r0 * C + c8);
        short8 v1 = *reinterpret_cast<const short8*>(src + (size_t)r1 * C + c8);
#pragma unroll
        for (int j = 0; j < 8; ++j)
            a[j] += b2f((unsigned short)v0[j]) + b2f((unsigned short)v1[j]);
    }
    if (i < e) {
        int r0 = list[i];
        short8 v0 = *reinterpret_cast<const short8*>(src + (size_t)r0 * C + c8);
#pragma unroll
        for (int j = 0; j < 8; ++j) a[j] += b2f((unsigned short)v0[j]);
    }
    const float sc = 1.0f / (float)max(e - s, 1);
    short8 o;
#pragma unroll
    for (int j = 0; j < 8; ++j) o[j] = (short)f2b(a[j] * sc);
    *reinterpret_cast<short8*>(dst + (size_t)node * C + c8) = o;
}

// ================= swapped-operand MFMA GEMM, W staged in LDS =================
// Y[u][h] = [relu]( X[u][:] @ W[h][:]^T + vec[h] )
template<int K, int NO, bool AVEC, bool RELU, bool F32OUT>
__global__ __launch_bounds__(256) void k_mf2(const unsigned short* __restrict__ X,
                                             const unsigned short* __restrict__ W,
                                             const float* __restrict__ vec,
                                             void* __restrict__ Yv, int M) {
    constexpr int KT = K / 32;
    constexpr int CG = NO / 16;
    constexpr int WB = NO * K * 2;         // weight bytes
    constexpr int RB = K * 2;              // row bytes
    __shared__ __align__(16) char lds[WB];
    const int tid = threadIdx.x;
    const int lane = tid & 63;
    const int wv = tid >> 6;
    const int rbase = blockIdx.x * 128 + wv * 32;
    const int lr = lane & 15;
    const int kg = lane >> 4;

    // stage W (coalesced, swizzled)
#pragma unroll
    for (int i = 0; i < WB / 16 / 256; ++i) {
        int idx = tid + i * 256;
        int row = idx / (RB / 16);
        int bc = (idx % (RB / 16)) * 16;
        *reinterpret_cast<uint4*>(lds + wswz(row, bc, RB)) =
            *reinterpret_cast<const uint4*>((const char*)W + idx * 16);
    }

    short8 xb[2][KT];
#pragma unroll
    for (int t = 0; t < 2; ++t) {
        int row = min(rbase + t * 16 + lr, M - 1);
#pragma unroll
        for (int kt = 0; kt < KT; ++kt)
            xb[t][kt] = *reinterpret_cast<const short8*>(
                X + (size_t)row * K + kt * 32 + kg * 8);
    }
    __syncthreads();

    f32x4 acc[2][CG];
#pragma unroll
    for (int t = 0; t < 2; ++t)
#pragma unroll
        for (int c = 0; c < CG; ++c) acc[t][c] = (f32x4){0.f, 0.f, 0.f, 0.f};

#pragma unroll
    for (int cg = 0; cg < CG; ++cg) {
        short8 wf[KT];
#pragma unroll
        for (int kt = 0; kt < KT; ++kt)
            wf[kt] = *reinterpret_cast<const short8*>(
                lds + wswz(cg * 16 + lr, kt * 64 + kg * 16, RB));
#pragma unroll
        for (int kt = 0; kt < KT; ++kt)
#pragma unroll
            for (int t = 0; t < 2; ++t)
                acc[t][cg] = __builtin_amdgcn_mfma_f32_16x16x32_bf16(
                    wf[kt], xb[t][kt], acc[t][cg], 0, 0, 0);
    }

#pragma unroll
    for (int t = 0; t < 2; ++t) {
        const int u = rbase + t * 16 + lr;
        if (u >= M) continue;
#pragma unroll
        for (int cg = 0; cg < CG; ++cg) {
            const int h0 = cg * 16 + kg * 4;
            float v[4];
#pragma unroll
            for (int r = 0; r < 4; ++r) v[r] = acc[t][cg][r];
            if (AVEC) {
                float4 vv = *reinterpret_cast<const float4*>(vec + h0);
                v[0] += vv.x; v[1] += vv.y; v[2] += vv.z; v[3] += vv.w;
            }
            if (RELU)
#pragma unroll
                for (int r = 0; r < 4; ++r) v[r] = fmaxf(v[r], 0.f);
            if (F32OUT) {
                float4 o = make_float4(v[0], v[1], v[2], v[3]);
                *reinterpret_cast<float4*>((float*)Yv + (size_t)u * NO + h0) = o;
            } else {
                uint2 o = make_uint2(pk2(v[0], v[1]), pk2(v[2], v[3]));
                *reinterpret_cast<uint2*>((unsigned short*)Yv + (size_t)u * NO + h0) = o;
            }
        }
    }
}

// ================= fused user chain (weights in LDS, Z aliases W3l) =================
// Z = relu(mean3@W3l^T + user_x@W3r^T + b3); out = Z@Wlin1^T + blin1
__global__ __launch_bounds__(256) void k_fused_u(
        const unsigned short* __restrict__ mean3, const unsigned short* __restrict__ user_x,
        const unsigned short* __restrict__ W3l, const unsigned short* __restrict__ W3r,
        const float* __restrict__ b3, const unsigned short* __restrict__ Wl1,
        const float* __restrict__ bl1, float* __restrict__ out, int M) {
    __shared__ __align__(16) char lds[65536];   // [0,32K) W3l -> Z; [32K,64K) W3r -> Wl1
    const int tid = threadIdx.x;
    const int lane = tid & 63;
    const int wv = tid >> 6;
    const int rbase = blockIdx.x * 128 + wv * 32;
    const int lr = lane & 15;
    const int kg = lane >> 4;

    // stage W3l + W3r (32KB each; 2048 16B-chunks; 16 chunks/row)
#pragma unroll
    for (int i = 0; i < 8; ++i) {
        int idx = tid + i * 256;
        int row = idx >> 4, bc = (idx & 15) << 4;
        int sw = wswz(row, bc, 256);
        *reinterpret_cast<uint4*>(lds + sw) =
            *reinterpret_cast<const uint4*>((const char*)W3l + idx * 16);
        *reinterpret_cast<uint4*>(lds + 32768 + sw) =
            *reinterpret_cast<const uint4*>((const char*)W3r + idx * 16);
    }

    short8 xa[2][4], xc[2][4];
#pragma unroll
    for (int t = 0; t < 2; ++t) {
        int row = min(rbase + t * 16 + lr, M - 1);
#pragma unroll
        for (int kt = 0; kt < 4; ++kt) {
            xa[t][kt] = *reinterpret_cast<const short8*>(
                mean3 + (size_t)row * HID + kt * 32 + kg * 8);
            xc[t][kt] = *reinterpret_cast<const short8*>(
                user_x + (size_t)row * HID + kt * 32 + kg * 8);
        }
    }
    __syncthreads();

    f32x4 acc[2][8];
#pragma unroll
    for (int t = 0; t < 2; ++t)
#pragma unroll
        for (int c = 0; c < 8; ++c) acc[t][c] = (f32x4){0.f, 0.f, 0.f, 0.f};

#pragma unroll
    for (int cg = 0; cg < 8; ++cg) {
        short8 wl[4], wr[4];
#pragma unroll
        for (int kt = 0; kt < 4; ++kt) {
            int sw = wswz(cg * 16 + lr, kt * 64 + kg * 16, 256);
            wl[kt] = *reinterpret_cast<const short8*>(lds + sw);
            wr[kt] = *reinterpret_cast<const short8*>(lds + 32768 + sw);
        }
#pragma unroll
        for (int kt = 0; kt < 4; ++kt)
#pragma unroll
            for (int t = 0; t < 2; ++t) {
                acc[t][cg] = __builtin_amdgcn_mfma_f32_16x16x32_bf16(
                    wl[kt], xa[t][kt], acc[t][cg], 0, 0, 0);
                acc[t][cg] = __builtin_amdgcn_mfma_f32_16x16x32_bf16(
                    wr[kt], xc[t][kt], acc[t][cg], 0, 0, 0);
            }
    }
    __syncthreads();   // all W3l/W3r reads done -> safe to overwrite

    // stage Wlin1 (16KB: [64][128] bf16, 256B rows) into upper half
#pragma unroll
    for (int i = 0; i < 4; ++i) {
        int idx = tid + i * 256;
        int row = idx >> 4, bc = (idx & 15) << 4;
        *reinterpret_cast<uint4*>(lds + 32768 + wswz(row, bc, 256)) =
            *reinterpret_cast<const uint4*>((const char*)Wl1 + idx * 16);
    }
    // epilogue 1: relu(acc + b3) -> swizzled Z tile over [0,32K)
#pragma unroll
    for (int t = 0; t < 2; ++t) {
        const int ul = wv * 32 + t * 16 + lr;
#pragma unroll
        for (int cg = 0; cg < 8; ++cg) {
            const int h0 = cg * 16 + kg * 4;
            float4 vv = *reinterpret_cast<const float4*>(b3 + h0);
            float v0 = fmaxf(acc[t][cg][0] + vv.x, 0.f);
            float v1 = fmaxf(acc[t][cg][1] + vv.y, 0.f);
            float v2 = fmaxf(acc[t][cg][2] + vv.z, 0.f);
            float v3 = fmaxf(acc[t][cg][3] + vv.w, 0.f);
            uint2 pk = make_uint2(pk2(v0, v1), pk2(v2, v3));
            *reinterpret_cast<uint2*>(lds + wswz(ul, h0 * 2, 256)) = pk;
        }
    }
    __syncthreads();

    // GEMM2: out = Z @ Wlin1^T + blin1 (all LDS-fed)
    short8 zb[2][4];
#pragma unroll
    for (int t = 0; t < 2; ++t) {
        const int ul = wv * 32 + t * 16 + lr;
#pragma unroll
        for (int kt = 0; kt < 4; ++kt)
            zb[t][kt] = *reinterpret_cast<const short8*>(
                lds + wswz(ul, kt * 64 + kg * 16, 256));
    }
    f32x4 a2[2][4];
#pragma unroll
    for (int t = 0; t < 2; ++t)
#pragma unroll
        for (int c = 0; c < 4; ++c) a2[t][c] = (f32x4){0.f, 0.f, 0.f, 0.f};
#pragma unroll
    for (int cg = 0; cg < 4; ++cg) {
        short8 wf[4];
#pragma unroll
        for (int kt = 0; kt < 4; ++kt)
            wf[kt] = *reinterpret_cast<const short8*>(
                lds + 32768 + wswz(cg * 16 + lr, kt * 64 + kg * 16, 256));
#pragma unroll
        for (int kt = 0; kt < 4; ++kt)
#pragma unroll
            for (int t = 0; t < 2; ++t)
                a2[t][cg] = __builtin_amdgcn_mfma_f32_16x16x32_bf16(
                    wf[kt], zb[t][kt], a2[t][cg], 0, 0, 0);
    }
#pragma unroll
    for (int t = 0; t < 2; ++t) {
        const int u = rbase + t * 16 + lr;
        if (u >= M) continue;
#pragma unroll
        for (int cg = 0; cg < 4; ++cg) {
            const int o0 = cg * 16 + kg * 4;
            float4 bb = *reinterpret_cast<const float4*>(bl1 + o0);
            float4 o = make_float4(a2[t][cg][0] + bb.x, a2[t][cg][1] + bb.y,
                                   a2[t][cg][2] + bb.z, a2[t][cg][3] + bb.w);
            *reinterpret_cast<float4*>(out + (size_t)u * OUTD + o0) = o;
        }
    }
}

// ================= fused movie chain (weights in LDS, Z aliases W2l) =================
// Z = relu(mean2@W2l^T + mxb@W2r^T + b2); movie_z = Z; out = Z@Wlin2^T + blin2
__global__ __launch_bounds__(256) void k_fused_m(
        const unsigned short* __restrict__ mean2, const unsigned short* __restrict__ mxb,
        const unsigned short* __restrict__ W2l, const unsigned short* __restrict__ W2r,
        const float* __restrict__ b2, unsigned short* __restrict__ movie_z,
        const unsigned short* __restrict__ Wl2, const float* __restrict__ bl2,
        float* __restrict__ out, int M) {
    __shared__ __align__(16) char lds[49152];   // [0,32K) W2l -> Z; [32K,48K) W2r -> Wl2
    const int tid = threadIdx.x;
    const int lane = tid & 63;
    const int wv = tid >> 6;
    const int rbase = blockIdx.x * 128 + wv * 32;
    const int lr = lane & 15;
    const int kg = lane >> 4;

    // stage W2l (32KB, 256B rows) and W2r (16KB, 128B rows)
#pragma unroll
    for (int i = 0; i < 8; ++i) {
        int idx = tid + i * 256;
        int row = idx >> 4, bc = (idx & 15) << 4;
        *reinterpret_cast<uint4*>(lds + wswz(row, bc, 256)) =
            *reinterpret_cast<const uint4*>((const char*)W2l + idx * 16);
    }
#pragma unroll
    for (int i = 0; i < 4; ++i) {
        int idx = tid + i * 256;
        int row = idx >> 3, bc = (idx & 7) << 4;
        *reinterpret_cast<uint4*>(lds + 32768 + wswz(row, bc, 128)) =
            *reinterpret_cast<const uint4*>((const char*)W2r + idx * 16);
    }

    short8 xa[2][4], xc[2][2];
#pragma unroll
    for (int t = 0; t < 2; ++t) {
        int row = min(rbase + t * 16 + lr, M - 1);
#pragma unroll
        for (int kt = 0; kt < 4; ++kt)
            xa[t][kt] = *reinterpret_cast<const short8*>(
                mean2 + (size_t)row * HID + kt * 32 + kg * 8);
#pragma unroll
        for (int kt = 0; kt < 2; ++kt)
            xc[t][kt] = *reinterpret_cast<const short8*>(
                mxb + (size_t)row * FEAT + kt * 32 + kg * 8);
    }
    __syncthreads();

    f32x4 acc[2][8];
#pragma unroll
    for (int t = 0; t < 2; ++t)
#pragma unroll
        for (int c = 0; c < 8; ++c) acc[t][c] = (f32x4){0.f, 0.f, 0.f, 0.f};

#pragma unroll
    for (int cg = 0; cg < 8; ++cg) {
        short8 wl[4], wr[2];
#pragma unroll
        for (int kt = 0; kt < 4; ++kt)
            wl[kt] = *reinterpret_cast<const short8*>(
                lds + wswz(cg * 16 + lr, kt * 64 + kg * 16, 256));
#pragma unroll
        for (int kt = 0; kt < 2; ++kt)
            wr[kt] = *reinterpret_cast<const short8*>(
                lds + 32768 + wswz(cg * 16 + lr, kt * 64 + kg * 16, 128));
#pragma unroll
        for (int kt = 0; kt < 4; ++kt)
#pragma unroll
            for (int t = 0; t < 2; ++t)
                acc[t][cg] = __builtin_amdgcn_mfma_f32_16x16x32_bf16(
                    wl[kt], xa[t][kt], acc[t][cg], 0, 0, 0);
#pragma unroll
        for (int kt = 0; kt < 2; ++kt)
#pragma unroll
            for (int t = 0; t < 2; ++t)
                acc[t][cg] = __builtin_amdgcn_mfma_f32_16x16x32_bf16(
                    wr[kt], xc[t][kt], acc[t][cg], 0, 0, 0);
    }
    __syncthreads();   // weight reads done -> safe to overwrite

    // stage Wlin2 (16KB, 256B rows) over W2r
#pragma unroll
    for (int i = 0; i < 4; ++i) {
        int idx = tid + i * 256;
        int row = idx >> 4, bc = (idx & 15) << 4;
        *reinterpret_cast<uint4*>(lds + 32768 + wswz(row, bc, 256)) =
            *reinterpret_cast<const uint4*>((const char*)Wl2 + idx * 16);
    }
    // epilogue 1: relu(acc + b2) -> Z (LDS) + global movie_z
#pragma unroll
    for (int t = 0; t < 2; ++t) {
        const int ul = wv * 32 + t * 16 + lr;
        const int u = rbase + t * 16 + lr;
#pragma unroll
        for (int cg = 0; cg < 8; ++cg) {
            const int h0 = cg * 16 + kg * 4;
            float4 vv = *reinterpret_cast<const float4*>(b2 + h0);
            float v0 = fmaxf(acc[t][cg][0] + vv.x, 0.f);
            float v1 = fmaxf(acc[t][cg][1] + vv.y, 0.f);
            float v2 = fmaxf(acc[t][cg][2] + vv.z, 0.f);
            float v3 = fmaxf(acc[t][cg][3] + vv.w, 0.f);
            uint2 pk = make_uint2(pk2(v0, v1), pk2(v2, v3));
            *reinterpret_cast<uint2*>(lds + wswz(ul, h0 * 2, 256)) = pk;
            if (u < M)
                *reinterpret_cast<uint2*>(movie_z + (size_t)u * HID + h0) = pk;
        }
    }
    __syncthreads();

    // GEMM2: out = Z @ Wlin2^T + blin2 (all LDS-fed)
    short8 zb[2][4];
#pragma unroll
    for (int t = 0; t < 2; ++t) {
        const int ul = wv * 32 + t * 16 + lr;
#pragma unroll
        for (int kt = 0; kt < 4; ++kt)
            zb[t][kt] = *reinterpret_cast<const short8*>(
                lds + wswz(ul, kt * 64 + kg * 16, 256));
    }
    f32x4 a2[2][4];
#pragma unroll
    for (int t = 0; t < 2; ++t)
#pragma unroll
        for (int c = 0; c < 4; ++c) a2[t][c] = (f32x4){0.f, 0.f, 0.f, 0.f};
#pragma unroll
    for (int cg = 0; cg < 4; ++cg) {
        short8 wf[4];
#pragma unroll
        for (int kt = 0; kt < 4; ++kt)
            wf[kt] = *reinterpret_cast<const short8*>(
                lds + 32768 + wswz(cg * 16 + lr, kt * 64 + kg * 16, 256));
#pragma unroll
        for (int kt = 0; kt < 4; ++kt)
#pragma unroll
            for (int t = 0; t < 2; ++t)
                a2[t][cg] = __builtin_amdgcn_mfma_f32_16x16x32_bf16(
                    wf[kt], zb[t][kt], a2[t][cg], 0, 0, 0);
    }
#pragma unroll
    for (int t = 0; t < 2; ++t) {
        const int u = rbase + t * 16 + lr;
        if (u >= M) continue;
#pragma unroll
        for (int cg = 0; cg < 4; ++cg) {
            const int o0 = cg * 16 + kg * 4;
            float4 bb = *reinterpret_cast<const float4*>(bl2 + o0);
            float4 o = make_float4(a2[t][cg][0] + bb.x, a2[t][cg][1] + bb.y,
                                   a2[t][cg][2] + bb.z, a2[t][cg][3] + bb.w);
            *reinterpret_cast<float4*>(out + (size_t)u * OUTD + o0) = o;
        }
    }
}

extern "C" void kernel_launch(void* const* d_in, const int* in_sizes, int n_in,
                              void* d_out, int out_size, void* d_ws, size_t ws_size,
                              hipStream_t stream) {
    const float* movie_x  = (const float*)d_in[0];
    const int*   user_idx = (const int*)d_in[1];
    const int*   movie_idx= (const int*)d_in[2];
    const int*   tuples   = (const int*)d_in[3];
    const float* user_emb = (const float*)d_in[4];
    const float* W1l = (const float*)d_in[5];
    const float* b1  = (const float*)d_in[6];
    const float* W1r = (const float*)d_in[7];
    const float* W2l = (const float*)d_in[8];
    const float* b2  = (const float*)d_in[9];
    const float* W2r = (const float*)d_in[10];
    const float* W3l = (const float*)d_in[11];
    const float* b3  = (const float*)d_in[12];
    const float* W3r = (const float*)d_in[13];
    const float* Wlin1 = (const float*)d_in[14];
    const float* blin1 = (const float*)d_in[15];
    const float* Wlin2 = (const float*)d_in[16];
    const float* blin2 = (const float*)d_in[17];

    float* out = (float*)d_out;

    // ---- workspace layout ----
    char* p = (char*)d_ws;
    int* ghist = (int*)p;  p += 360 * 4;
    int* bb    = (int*)p;  p += 360 * 4;
    int* gcur  = (int*)p;  p += 360 * 4;
    int* entries = (int*)p; p += (size_t)NLIST * 4;
    int* rp    = (int*)p;  p += (size_t)(NTOT + 8) * 4;
    int* list  = (int*)p;  p += (size_t)NLIST * 4;
    float* c1  = (float*)p; p += 128 * 4;
    unsigned short* wb = (unsigned short*)p; p += (size_t)CVT_TOT * 2;
    unsigned short* W1l_b  = wb;
    unsigned short* W2l_b  = wb + 8192;
    unsigned short* W2r_b  = wb + 24576;
    unsigned short* W3l_b  = wb + 32768;
    unsigned short* W3r_b  = wb + 49152;
    unsigned short* Wlin1_b= wb + 65536;
    unsigned short* Wlin2_b= wb + 73728;
    unsigned short* mxb    = wb + 81920;                              // [NM][64]
    unsigned short* mean1  = (unsigned short*)p; p += (size_t)NU * FEAT * 2;
    unsigned short* user_x = (unsigned short*)p; p += (size_t)NU * HID * 2;
    unsigned short* mean2  = (unsigned short*)p; p += (size_t)NM * HID * 2;
    unsigned short* movie_z= (unsigned short*)p; p += (size_t)NM * HID * 2;
    unsigned short* mean3  = (unsigned short*)p; p += (size_t)NU * HID * 2;

    // ---- CSR build ----
    hipMemsetAsync(ghist, 0, NBUCK * sizeof(int), stream);
    k_hist<<<NPBLK, 256, 0, stream>>>(user_idx, movie_idx, ghist);
    k_bscan<<<1, 512, 0, stream>>>(ghist, bb, gcur);
    k_part<<<NPBLK, 256, 0, stream>>>(user_idx, movie_idx, gcur, entries);
    k_csr<<<NBUCK, 256, 0, stream>>>(bb, entries, rp, list);

    // ---- merged small work: conversions + new_index + c1 ----
    k_misc<<<CVT_BLKS + IDX_BLKS + 1, 256, 0, stream>>>(
        W1l, W2l, W2r, W3l, W3r, Wlin1, Wlin2, movie_x, wb,
        tuples, out + (size_t)(NU + NM) * OUTD, user_emb, W1r, b1, c1);

    // ---- conv1: gather (high-TLP) + GEMM -> user_x ----
    k_gather_b<FEAT><<<(NU + 31) / 32, 256, 0, stream>>>(mxb, rp, list, mean1, 0, NU);
    k_mf2<FEAT, HID, true, true, false><<<(NU + 127) / 128, 256, 0, stream>>>(
        mean1, W1l_b, c1, user_x, NU);

    // ---- conv2 + lin2 (fused movie chain) ----
    k_gather_b<HID><<<(NM + 15) / 16, 256, 0, stream>>>(user_x, rp, list, mean2, NU, NM);
    k_fused_m<<<(NM + 127) / 128, 256, 0, stream>>>(
        mean2, mxb, W2l_b, W2r_b, b2, movie_z, Wlin2_b, blin2,
        out + (size_t)NU * OUTD, NM);

    // ---- conv3 + lin1 (fused user chain; t3 computed inline from user_x) ----
    k_gather_b<HID><<<(NU + 15) / 16, 256, 0, stream>>>(movie_z, rp, list, mean3, 0, NU);
    k_fused_u<<<(NU + 127) / 128, 256, 0, stream>>>(
        mean3, user_x, W3l_b, W3r_b, b3, Wlin1_b, blin1, out, NU);
}

// Round 10
// 167.249 us; speedup vs baseline: 1.8134x; 1.0956x over previous
//
#include <hip/hip_runtime.h>

typedef __attribute__((ext_vector_type(8))) short short8;   // 8 bf16 (4 VGPR)
typedef __attribute__((ext_vector_type(4))) float f32x4;    // MFMA acc

static const int NU = 100000;
static const int NM = 20000;
static const int NE = 600000;
static const int FEAT = 64;
static const int HID = 128;
static const int OUTD = 64;
static const int NTOT = NU + NM;
static const int NLIST = 2 * NE;
static const int CVT_TOT = 81920 + NM * FEAT;   // weights + movie_x
static const int CVT_BLKS = (CVT_TOT + 255) / 256;
static const int IDX_BLKS = (100000 + 255) / 256;

// bucket geometry: users 512 nodes/bucket, movies 128 nodes/bucket
static const int UB_SHIFT = 9;
static const int MB_SHIFT = 7;
static const int NBU = (NU + 511) >> 9;           // 196
static const int NBM = (NM + 127) >> 7;           // 157
static const int NBUCK = NBU + NBM;               // 353
static const int EPB = 4096;
static const int NPBLK = (NE + EPB - 1) / EPB;    // 147

__device__ inline float b2f(unsigned short h) {
    unsigned int u = ((unsigned int)h) << 16;
    float f; __builtin_memcpy(&f, &u, 4); return f;
}
__device__ inline unsigned short f2b(float f) {
    unsigned int u; __builtin_memcpy(&u, &f, 4);
    u += 0x7FFFu + ((u >> 16) & 1u);            // RNE
    return (unsigned short)(u >> 16);
}
__device__ inline unsigned int pk2(float a, float b) {
    return (unsigned int)f2b(a) | ((unsigned int)f2b(b) << 16);
}
// XOR swizzle within a row: spreads 16B frag slots across banks (G4)
__device__ inline int wswz(int row, int bc, int rowbytes) {
    return row * rowbytes + (bc ^ ((row & 7) << 4));
}

// ---------------- pass 1 merged: bucket histogram + cvt + new_index + c1 ----------------
__global__ __launch_bounds__(256) void k_hist_misc(
        const int* __restrict__ ui, const int* __restrict__ mi, int* __restrict__ ghist,
        const float* __restrict__ w1l, const float* __restrict__ w2l,
        const float* __restrict__ w2r, const float* __restrict__ w3l,
        const float* __restrict__ w3r, const float* __restrict__ wl1,
        const float* __restrict__ wl2, const float* __restrict__ mx,
        unsigned short* __restrict__ dst,
        const int* __restrict__ tpl, float* __restrict__ oidx,
        const float* __restrict__ ue, const float* __restrict__ w1r,
        const float* __restrict__ b1, float* __restrict__ c1) {
    __shared__ int h[NBUCK];
    const int b = blockIdx.x;
    const int tid = threadIdx.x;
    if (b < NPBLK) {
        for (int i = tid; i < NBUCK; i += 256) h[i] = 0;
        __syncthreads();
#pragma unroll
        for (int it = 0; it < EPB / 256; ++it) {
            int e = b * EPB + it * 256 + tid;
            if (e < NE) {
                atomicAdd(&h[ui[e] >> UB_SHIFT], 1);
                atomicAdd(&h[NBU + (mi[e] >> MB_SHIFT)], 1);
            }
        }
        __syncthreads();
        for (int i = tid; i < NBUCK; i += 256)
            if (h[i]) atomicAdd(&ghist[i], h[i]);
    } else if (b < NPBLK + CVT_BLKS) {
        int g = (b - NPBLK) * 256 + tid;
        if (g >= CVT_TOT) return;
        const float* s; int o;
        if      (g < 8192)   { s = w1l; o = g; }
        else if (g < 24576)  { s = w2l; o = g - 8192; }
        else if (g < 32768)  { s = w2r; o = g - 24576; }
        else if (g < 49152)  { s = w3l; o = g - 32768; }
        else if (g < 65536)  { s = w3r; o = g - 49152; }
        else if (g < 73728)  { s = wl1; o = g - 65536; }
        else if (g < 81920)  { s = wl2; o = g - 73728; }
        else                 { s = mx;  o = g - 81920; }
        dst[g] = f2b(s[o]);
    } else if (b < NPBLK + CVT_BLKS + IDX_BLKS) {
        int i = (b - NPBLK - CVT_BLKS) * 256 + tid;
        if (i < 100000) {
            oidx[i] = (float)tpl[i];
            oidx[100000 + i] = (float)(tpl[100000 + i] + NU);
        }
    } else {
        int hh = tid;
        if (hh < HID) {
            float a = 0.f;
#pragma unroll 16
            for (int k = 0; k < HID; ++k) a += ue[k] * w1r[hh * HID + k];
            c1[hh] = a + b1[hh];
        }
    }
}

__global__ __launch_bounds__(512) void k_bscan(const int* __restrict__ ghist,
                                               int* __restrict__ bb,
                                               int* __restrict__ gcur) {
    __shared__ int s[512];
    const int tid = threadIdx.x;
    int v = (tid < NBUCK) ? ghist[tid] : 0;
    s[tid] = v;
    __syncthreads();
#pragma unroll
    for (int off = 1; off < 512; off <<= 1) {
        int x = (tid >= off) ? s[tid - off] : 0;
        __syncthreads();
        s[tid] += x;
        __syncthreads();
    }
    int excl = s[tid] - v;
    if (tid < NBUCK) { bb[tid] = excl; gcur[tid] = excl; }
    if (tid == 511) bb[NBUCK] = s[511];
}

__global__ __launch_bounds__(256) void k_part(const int* __restrict__ ui,
                                              const int* __restrict__ mi,
                                              int* __restrict__ gcur,
                                              int* __restrict__ entries) {
    __shared__ int h[NBUCK], base[NBUCK], cur[NBUCK];
    const int tid = threadIdx.x;
    for (int i = tid; i < NBUCK; i += 256) h[i] = 0;
    __syncthreads();

    int eu[EPB / 256], em[EPB / 256];
#pragma unroll
    for (int it = 0; it < EPB / 256; ++it) {
        int e = blockIdx.x * EPB + it * 256 + tid;
        if (e < NE) {
            eu[it] = ui[e]; em[it] = mi[e];
            atomicAdd(&h[eu[it] >> UB_SHIFT], 1);
            atomicAdd(&h[NBU + (em[it] >> MB_SHIFT)], 1);
        } else eu[it] = -1;
    }
    __syncthreads();
    for (int i = tid; i < NBUCK; i += 256) {
        int c = h[i];
        base[i] = c ? atomicAdd(&gcur[i], c) : 0;
        cur[i] = 0;
    }
    __syncthreads();
#pragma unroll
    for (int it = 0; it < EPB / 256; ++it) {
        if (eu[it] < 0) continue;
        int u = eu[it], m = em[it];
        int bu = u >> UB_SHIFT;
        int o1 = base[bu] + atomicAdd(&cur[bu], 1);
        entries[o1] = (m << UB_SHIFT) | (u & 511);
        int bm = NBU + (m >> MB_SHIFT);
        int o2 = base[bm] + atomicAdd(&cur[bm], 1);
        entries[o2] = (u << MB_SHIFT) | (m & 127);
    }
}

__global__ __launch_bounds__(256) void k_csr(const int* __restrict__ bb,
                                             const int* __restrict__ entries,
                                             int* __restrict__ rp,
                                             int* __restrict__ list) {
    __shared__ int lcnt[512], lrp[512], lcur[512], ps[256];
    const int b = blockIdx.x;
    const int tid = threadIdx.x;
    const int s = bb[b], e = bb[b + 1];
    const bool isU = b < NBU;
    const int shift = isU ? UB_SHIFT : MB_SHIFT;
    const int mask = isU ? 511 : 127;
    const int n0 = isU ? (b << UB_SHIFT) : ((b - NBU) << MB_SHIFT);
    const int nNodes = isU ? min(512, NU - n0) : min(128, NM - n0);
    const int g0 = isU ? n0 : NU + n0;

    for (int i = tid; i < 512; i += 256) { lcnt[i] = 0; lcur[i] = 0; }
    __syncthreads();
    for (int i = s + tid; i < e; i += 256)
        atomicAdd(&lcnt[entries[i] & mask], 1);
    __syncthreads();
    int a0 = lcnt[2 * tid], a1 = lcnt[2 * tid + 1];
    int pr = a0 + a1;
    ps[tid] = pr;
    __syncthreads();
#pragma unroll
    for (int off = 1; off < 256; off <<= 1) {
        int x = (tid >= off) ? ps[tid - off] : 0;
        __syncthreads();
        ps[tid] += x;
        __syncthreads();
    }
    int excl = ps[tid] - pr;
    lrp[2 * tid] = excl;
    lrp[2 * tid + 1] = excl + a0;
    __syncthreads();
    for (int i = tid; i < nNodes; i += 256) rp[g0 + i] = s + lrp[i];
    if (b == NBUCK - 1 && tid == 0) rp[NTOT] = e;
    for (int i = s + tid; i < e; i += 256) {
        int p = entries[i];
        int dl = p & mask;
        int off = s + lrp[dl] + atomicAdd(&lcur[dl], 1);
        list[off] = p >> shift;
    }
}

// ---------------- bf16 gather-based segment mean (high-TLP, standalone) ----------------
template<int C>
__global__ __launch_bounds__(256) void k_gather_b(const unsigned short* __restrict__ src,
                                                  const int* __restrict__ rp,
                                                  const int* __restrict__ list,
                                                  unsigned short* __restrict__ dst,
                                                  int base, int n) {
    constexpr int TPN = C / 8;
    constexpr int NPB = 256 / TPN;
    const int node = blockIdx.x * NPB + threadIdx.x / TPN;
    if (node >= n) return;
    const int c8 = (threadIdx.x % TPN) * 8;
    const int g = base + node;
    const int s = rp[g], e = rp[g + 1];

    float a[8];
#pragma unroll
    for (int j = 0; j < 8; ++j) a[j] = 0.f;

    int i = s;
    for (; i + 1 < e; i += 2) {
        int r0 = list[i], r1 = list[i + 1];
        short8 v0 = *reinterpret_cast<const short8*>(src + (size_t)r0 * C + c8);
        short8 v1 = *reinterpret_cast<const short8*>(src + (size_t)r1 * C + c8);
#pragma unroll
        for (int j = 0; j < 8; ++j)
            a[j] += b2f((unsigned short)v0[j]) + b2f((unsigned short)v1[j]);
    }
    if (i < e) {
        int r0 = list[i];
        short8 v0 = *reinterpret_cast<const short8*>(src + (size_t)r0 * C + c8);
#pragma unroll
        for (int j = 0; j < 8; ++j) a[j] += b2f((unsigned short)v0[j]);
    }
    const float sc = 1.0f / (float)max(e - s, 1);
    short8 o;
#pragma unroll
    for (int j = 0; j < 8; ++j) o[j] = (short)f2b(a[j] * sc);
    *reinterpret_cast<short8*>(dst + (size_t)node * C + c8) = o;
}

// ================= swapped-operand MFMA GEMM, W staged in LDS =================
template<int K, int NO, bool AVEC, bool RELU, bool F32OUT>
__global__ __launch_bounds__(256) void k_mf2(const unsigned short* __restrict__ X,
                                             const unsigned short* __restrict__ W,
                                             const float* __restrict__ vec,
                                             void* __restrict__ Yv, int M) {
    constexpr int KT = K / 32;
    constexpr int CG = NO / 16;
    constexpr int WB = NO * K * 2;
    constexpr int RB = K * 2;
    __shared__ __align__(16) char lds[WB];
    const int tid = threadIdx.x;
    const int lane = tid & 63;
    const int wv = tid >> 6;
    const int rbase = blockIdx.x * 128 + wv * 32;
    const int lr = lane & 15;
    const int kg = lane >> 4;

#pragma unroll
    for (int i = 0; i < WB / 16 / 256; ++i) {
        int idx = tid + i * 256;
        int row = idx / (RB / 16);
        int bc = (idx % (RB / 16)) * 16;
        *reinterpret_cast<uint4*>(lds + wswz(row, bc, RB)) =
            *reinterpret_cast<const uint4*>((const char*)W + idx * 16);
    }

    short8 xb[2][KT];
#pragma unroll
    for (int t = 0; t < 2; ++t) {
        int row = min(rbase + t * 16 + lr, M - 1);
#pragma unroll
        for (int kt = 0; kt < KT; ++kt)
            xb[t][kt] = *reinterpret_cast<const short8*>(
                X + (size_t)row * K + kt * 32 + kg * 8);
    }
    __syncthreads();

    f32x4 acc[2][CG];
#pragma unroll
    for (int t = 0; t < 2; ++t)
#pragma unroll
        for (int c = 0; c < CG; ++c) acc[t][c] = (f32x4){0.f, 0.f, 0.f, 0.f};

#pragma unroll
    for (int cg = 0; cg < CG; ++cg) {
        short8 wf[KT];
#pragma unroll
        for (int kt = 0; kt < KT; ++kt)
            wf[kt] = *reinterpret_cast<const short8*>(
                lds + wswz(cg * 16 + lr, kt * 64 + kg * 16, RB));
#pragma unroll
        for (int kt = 0; kt < KT; ++kt)
#pragma unroll
            for (int t = 0; t < 2; ++t)
                acc[t][cg] = __builtin_amdgcn_mfma_f32_16x16x32_bf16(
                    wf[kt], xb[t][kt], acc[t][cg], 0, 0, 0);
    }

#pragma unroll
    for (int t = 0; t < 2; ++t) {
        const int u = rbase + t * 16 + lr;
        if (u >= M) continue;
#pragma unroll
        for (int cg = 0; cg < CG; ++cg) {
            const int h0 = cg * 16 + kg * 4;
            float v[4];
#pragma unroll
            for (int r = 0; r < 4; ++r) v[r] = acc[t][cg][r];
            if (AVEC) {
                float4 vv = *reinterpret_cast<const float4*>(vec + h0);
                v[0] += vv.x; v[1] += vv.y; v[2] += vv.z; v[3] += vv.w;
            }
            if (RELU)
#pragma unroll
                for (int r = 0; r < 4; ++r) v[r] = fmaxf(v[r], 0.f);
            if (F32OUT) {
                float4 o = make_float4(v[0], v[1], v[2], v[3]);
                *reinterpret_cast<float4*>((float*)Yv + (size_t)u * NO + h0) = o;
            } else {
                uint2 o = make_uint2(pk2(v[0], v[1]), pk2(v[2], v[3]));
                *reinterpret_cast<uint2*>((unsigned short*)Yv + (size_t)u * NO + h0) = o;
            }
        }
    }
}

// ================= fused user chain (slim: W3l pushed through mean as S3 carry) =================
// Z = relu(S3 + user_x@W3r^T + b3); out = Z@Wlin1^T + blin1
__global__ __launch_bounds__(256) void k_fused_u(
        const unsigned short* __restrict__ S3, const unsigned short* __restrict__ user_x,
        const unsigned short* __restrict__ W3r, const float* __restrict__ b3,
        const unsigned short* __restrict__ Wl1, const float* __restrict__ bl1,
        float* __restrict__ out, int M) {
    __shared__ __align__(16) char lds[49152];   // [0,32K) W3r -> Z; [32K,48K) Wl1 (upfront)
    const int tid = threadIdx.x;
    const int lane = tid & 63;
    const int wv = tid >> 6;
    const int rbase = blockIdx.x * 128 + wv * 32;
    const int lr = lane & 15;
    const int kg = lane >> 4;

    // stage W3r (32KB, 256B rows) + Wl1 (16KB, 256B rows)
#pragma unroll
    for (int i = 0; i < 8; ++i) {
        int idx = tid + i * 256;
        int row = idx >> 4, bc = (idx & 15) << 4;
        *reinterpret_cast<uint4*>(lds + wswz(row, bc, 256)) =
            *reinterpret_cast<const uint4*>((const char*)W3r + idx * 16);
    }
#pragma unroll
    for (int i = 0; i < 4; ++i) {
        int idx = tid + i * 256;
        int row = idx >> 4, bc = (idx & 15) << 4;
        *reinterpret_cast<uint4*>(lds + 32768 + wswz(row, bc, 256)) =
            *reinterpret_cast<const uint4*>((const char*)Wl1 + idx * 16);
    }

    short8 xc[2][4];
#pragma unroll
    for (int t = 0; t < 2; ++t) {
        int row = min(rbase + t * 16 + lr, M - 1);
#pragma unroll
        for (int kt = 0; kt < 4; ++kt)
            xc[t][kt] = *reinterpret_cast<const short8*>(
                user_x + (size_t)row * HID + kt * 32 + kg * 8);
    }
    __syncthreads();

    f32x4 acc[2][8];
#pragma unroll
    for (int t = 0; t < 2; ++t)
#pragma unroll
        for (int c = 0; c < 8; ++c) acc[t][c] = (f32x4){0.f, 0.f, 0.f, 0.f};

#pragma unroll
    for (int cg = 0; cg < 8; ++cg) {
        short8 wr[4];
#pragma unroll
        for (int kt = 0; kt < 4; ++kt)
            wr[kt] = *reinterpret_cast<const short8*>(
                lds + wswz(cg * 16 + lr, kt * 64 + kg * 16, 256));
#pragma unroll
        for (int kt = 0; kt < 4; ++kt)
#pragma unroll
            for (int t = 0; t < 2; ++t)
                acc[t][cg] = __builtin_amdgcn_mfma_f32_16x16x32_bf16(
                    wr[kt], xc[t][kt], acc[t][cg], 0, 0, 0);
    }
    __syncthreads();   // W3r reads done -> Z may overwrite

    // epilogue: Z = relu(acc + S3 + b3) -> swizzled LDS
#pragma unroll
    for (int t = 0; t < 2; ++t) {
        const int ul = wv * 32 + t * 16 + lr;
        const int u = min(rbase + t * 16 + lr, M - 1);
#pragma unroll
        for (int cg = 0; cg < 8; ++cg) {
            const int h0 = cg * 16 + kg * 4;
            uint2 s3 = *reinterpret_cast<const uint2*>(S3 + (size_t)u * HID + h0);
            float4 vv = *reinterpret_cast<const float4*>(b3 + h0);
            float v0 = fmaxf(acc[t][cg][0] + b2f((unsigned short)(s3.x & 0xffff)) + vv.x, 0.f);
            float v1 = fmaxf(acc[t][cg][1] + b2f((unsigned short)(s3.x >> 16)) + vv.y, 0.f);
            float v2 = fmaxf(acc[t][cg][2] + b2f((unsigned short)(s3.y & 0xffff)) + vv.z, 0.f);
            float v3 = fmaxf(acc[t][cg][3] + b2f((unsigned short)(s3.y >> 16)) + vv.w, 0.f);
            uint2 pk = make_uint2(pk2(v0, v1), pk2(v2, v3));
            *reinterpret_cast<uint2*>(lds + wswz(ul, h0 * 2, 256)) = pk;
        }
    }
    __syncthreads();

    // GEMM2: out = Z @ Wlin1^T + blin1
    short8 zb[2][4];
#pragma unroll
    for (int t = 0; t < 2; ++t) {
        const int ul = wv * 32 + t * 16 + lr;
#pragma unroll
        for (int kt = 0; kt < 4; ++kt)
            zb[t][kt] = *reinterpret_cast<const short8*>(
                lds + wswz(ul, kt * 64 + kg * 16, 256));
    }
    f32x4 a2[2][4];
#pragma unroll
    for (int t = 0; t < 2; ++t)
#pragma unroll
        for (int c = 0; c < 4; ++c) a2[t][c] = (f32x4){0.f, 0.f, 0.f, 0.f};
#pragma unroll
    for (int cg = 0; cg < 4; ++cg) {
        short8 wf[4];
#pragma unroll
        for (int kt = 0; kt < 4; ++kt)
            wf[kt] = *reinterpret_cast<const short8*>(
                lds + 32768 + wswz(cg * 16 + lr, kt * 64 + kg * 16, 256));
#pragma unroll
        for (int kt = 0; kt < 4; ++kt)
#pragma unroll
            for (int t = 0; t < 2; ++t)
                a2[t][cg] = __builtin_amdgcn_mfma_f32_16x16x32_bf16(
                    wf[kt], zb[t][kt], a2[t][cg], 0, 0, 0);
    }
#pragma unroll
    for (int t = 0; t < 2; ++t) {
        const int u = rbase + t * 16 + lr;
        if (u >= M) continue;
#pragma unroll
        for (int cg = 0; cg < 4; ++cg) {
            const int o0 = cg * 16 + kg * 4;
            float4 bb = *reinterpret_cast<const float4*>(bl1 + o0);
            float4 o = make_float4(a2[t][cg][0] + bb.x, a2[t][cg][1] + bb.y,
                                   a2[t][cg][2] + bb.z, a2[t][cg][3] + bb.w);
            *reinterpret_cast<float4*>(out + (size_t)u * OUTD + o0) = o;
        }
    }
}

// ================= fused movie chain + Y3 projection =================
// Z = relu(mean2@W2l^T + mxb@W2r^T + b2); movie_z = Z; out = Z@Wlin2^T + blin2;
// Y3 = Z @ W3l^T  (push-through for conv3)
__global__ __launch_bounds__(256) void k_fused_m(
        const unsigned short* __restrict__ mean2, const unsigned short* __restrict__ mxb,
        const unsigned short* __restrict__ W2l, const unsigned short* __restrict__ W2r,
        const float* __restrict__ b2, unsigned short* __restrict__ movie_z,
        const unsigned short* __restrict__ Wl2, const float* __restrict__ bl2,
        const unsigned short* __restrict__ W3l, unsigned short* __restrict__ Y3,
        float* __restrict__ out, int M) {
    __shared__ __align__(16) char lds[65536];
    // [0,32K) W2l -> Z; [32K,48K) W2r -> W3l(lo); [48K,64K) Wl2 -> W3l(hi)
    const int tid = threadIdx.x;
    const int lane = tid & 63;
    const int wv = tid >> 6;
    const int rbase = blockIdx.x * 128 + wv * 32;
    const int lr = lane & 15;
    const int kg = lane >> 4;

    // stage W2l (32KB, 256B rows), W2r (16KB, 128B rows), Wl2 (16KB, 256B rows)
#pragma unroll
    for (int i = 0; i < 8; ++i) {
        int idx = tid + i * 256;
        int row = idx >> 4, bc = (idx & 15) << 4;
        *reinterpret_cast<uint4*>(lds + wswz(row, bc, 256)) =
            *reinterpret_cast<const uint4*>((const char*)W2l + idx * 16);
    }
#pragma unroll
    for (int i = 0; i < 4; ++i) {
        int idx = tid + i * 256;
        int row = idx >> 3, bc = (idx & 7) << 4;
        *reinterpret_cast<uint4*>(lds + 32768 + wswz(row, bc, 128)) =
            *reinterpret_cast<const uint4*>((const char*)W2r + idx * 16);
        int row2 = idx >> 4, bc2 = (idx & 15) << 4;
        *reinterpret_cast<uint4*>(lds + 49152 + wswz(row2, bc2, 256)) =
            *reinterpret_cast<const uint4*>((const char*)Wl2 + idx * 16);
    }

    short8 xa[2][4], xc[2][2];
#pragma unroll
    for (int t = 0; t < 2; ++t) {
        int row = min(rbase + t * 16 + lr, M - 1);
#pragma unroll
        for (int kt = 0; kt < 4; ++kt)
            xa[t][kt] = *reinterpret_cast<const short8*>(
                mean2 + (size_t)row * HID + kt * 32 + kg * 8);
#pragma unroll
        for (int kt = 0; kt < 2; ++kt)
            xc[t][kt] = *reinterpret_cast<const short8*>(
                mxb + (size_t)row * FEAT + kt * 32 + kg * 8);
    }
    __syncthreads();

    f32x4 acc[2][8];
#pragma unroll
    for (int t = 0; t < 2; ++t)
#pragma unroll
        for (int c = 0; c < 8; ++c) acc[t][c] = (f32x4){0.f, 0.f, 0.f, 0.f};

#pragma unroll
    for (int cg = 0; cg < 8; ++cg) {
        short8 wl[4], wr[2];
#pragma unroll
        for (int kt = 0; kt < 4; ++kt)
            wl[kt] = *reinterpret_cast<const short8*>(
                lds + wswz(cg * 16 + lr, kt * 64 + kg * 16, 256));
#pragma unroll
        for (int kt = 0; kt < 2; ++kt)
            wr[kt] = *reinterpret_cast<const short8*>(
                lds + 32768 + wswz(cg * 16 + lr, kt * 64 + kg * 16, 128));
#pragma unroll
        for (int kt = 0; kt < 4; ++kt)
#pragma unroll
            for (int t = 0; t < 2; ++t)
                acc[t][cg] = __builtin_amdgcn_mfma_f32_16x16x32_bf16(
                    wl[kt], xa[t][kt], acc[t][cg], 0, 0, 0);
#pragma unroll
        for (int kt = 0; kt < 2; ++kt)
#pragma unroll
            for (int t = 0; t < 2; ++t)
                acc[t][cg] = __builtin_amdgcn_mfma_f32_16x16x32_bf16(
                    wr[kt], xc[t][kt], acc[t][cg], 0, 0, 0);
    }
    __syncthreads();   // W2l reads done -> Z may overwrite [0,32K)

    // epilogue 1: relu(acc + b2) -> Z (LDS) + global movie_z
#pragma unroll
    for (int t = 0; t < 2; ++t) {
        const int ul = wv * 32 + t * 16 + lr;
        const int u = rbase + t * 16 + lr;
#pragma unroll
        for (int cg = 0; cg < 8; ++cg) {
            const int h0 = cg * 16 + kg * 4;
            float4 vv = *reinterpret_cast<const float4*>(b2 + h0);
            float v0 = fmaxf(acc[t][cg][0] + vv.x, 0.f);
            float v1 = fmaxf(acc[t][cg][1] + vv.y, 0.f);
            float v2 = fmaxf(acc[t][cg][2] + vv.z, 0.f);
            float v3 = fmaxf(acc[t][cg][3] + vv.w, 0.f);
            uint2 pk = make_uint2(pk2(v0, v1), pk2(v2, v3));
            *reinterpret_cast<uint2*>(lds + wswz(ul, h0 * 2, 256)) = pk;
            if (u < M)
                *reinterpret_cast<uint2*>(movie_z + (size_t)u * HID + h0) = pk;
        }
    }
    __syncthreads();

    // GEMM2: out = Z @ Wlin2^T + blin2 (Z at [0,32K), Wl2 at [48K,64K))
    short8 zb[2][4];
#pragma unroll
    for (int t = 0; t < 2; ++t) {
        const int ul = wv * 32 + t * 16 + lr;
#pragma unroll
        for (int kt = 0; kt < 4; ++kt)
            zb[t][kt] = *reinterpret_cast<const short8*>(
                lds + wswz(ul, kt * 64 + kg * 16, 256));
    }
    f32x4 a2[2][4];
#pragma unroll
    for (int t = 0; t < 2; ++t)
#pragma unroll
        for (int c = 0; c < 4; ++c) a2[t][c] = (f32x4){0.f, 0.f, 0.f, 0.f};
#pragma unroll
    for (int cg = 0; cg < 4; ++cg) {
        short8 wf[4];
#pragma unroll
        for (int kt = 0; kt < 4; ++kt)
            wf[kt] = *reinterpret_cast<const short8*>(
                lds + 49152 + wswz(cg * 16 + lr, kt * 64 + kg * 16, 256));
#pragma unroll
        for (int kt = 0; kt < 4; ++kt)
#pragma unroll
            for (int t = 0; t < 2; ++t)
                a2[t][cg] = __builtin_amdgcn_mfma_f32_16x16x32_bf16(
                    wf[kt], zb[t][kt], a2[t][cg], 0, 0, 0);
    }
#pragma unroll
    for (int t = 0; t < 2; ++t) {
        const int u = rbase + t * 16 + lr;
        if (u >= M) continue;
#pragma unroll
        for (int cg = 0; cg < 4; ++cg) {
            const int o0 = cg * 16 + kg * 4;
            float4 bb = *reinterpret_cast<const float4*>(bl2 + o0);
            float4 o = make_float4(a2[t][cg][0] + bb.x, a2[t][cg][1] + bb.y,
                                   a2[t][cg][2] + bb.z, a2[t][cg][3] + bb.w);
            *reinterpret_cast<float4*>(out + (size_t)u * OUTD + o0) = o;
        }
    }
    __syncthreads();   // Wl2 + W2r reads done -> W3l may overwrite [32K,64K)

    // stage W3l (32KB, 256B rows) at [32K,64K)
#pragma unroll
    for (int i = 0; i < 8; ++i) {
        int idx = tid + i * 256;
        int row = idx >> 4, bc = (idx & 15) << 4;
        *reinterpret_cast<uint4*>(lds + 32768 + wswz(row, bc, 256)) =
            *reinterpret_cast<const uint4*>((const char*)W3l + idx * 16);
    }
    __syncthreads();

    // GEMM3: Y3 = Z @ W3l^T  (zb frags reused)
    f32x4 a3[2][8];
#pragma unroll
    for (int t = 0; t < 2; ++t)
#pragma unroll
        for (int c = 0; c < 8; ++c) a3[t][c] = (f32x4){0.f, 0.f, 0.f, 0.f};
#pragma unroll
    for (int cg = 0; cg < 8; ++cg) {
        short8 wf[4];
#pragma unroll
        for (int kt = 0; kt < 4; ++kt)
            wf[kt] = *reinterpret_cast<const short8*>(
                lds + 32768 + wswz(cg * 16 + lr, kt * 64 + kg * 16, 256));
#pragma unroll
        for (int kt = 0; kt < 4; ++kt)
#pragma unroll
            for (int t = 0; t < 2; ++t)
                a3[t][cg] = __builtin_amdgcn_mfma_f32_16x16x32_bf16(
                    wf[kt], zb[t][kt], a3[t][cg], 0, 0, 0);
    }
#pragma unroll
    for (int t = 0; t < 2; ++t) {
        const int u = rbase + t * 16 + lr;
        if (u >= M) continue;
#pragma unroll
        for (int cg = 0; cg < 8; ++cg) {
            const int h0 = cg * 16 + kg * 4;
            uint2 pk = make_uint2(pk2(a3[t][cg][0], a3[t][cg][1]),
                                  pk2(a3[t][cg][2], a3[t][cg][3]));
            *reinterpret_cast<uint2*>(Y3 + (size_t)u * HID + h0) = pk;
        }
    }
}

extern "C" void kernel_launch(void* const* d_in, const int* in_sizes, int n_in,
                              void* d_out, int out_size, void* d_ws, size_t ws_size,
                              hipStream_t stream) {
    const float* movie_x  = (const float*)d_in[0];
    const int*   user_idx = (const int*)d_in[1];
    const int*   movie_idx= (const int*)d_in[2];
    const int*   tuples   = (const int*)d_in[3];
    const float* user_emb = (const float*)d_in[4];
    const float* W1l = (const float*)d_in[5];
    const float* b1  = (const float*)d_in[6];
    const float* W1r = (const float*)d_in[7];
    const float* W2l = (const float*)d_in[8];
    const float* b2  = (const float*)d_in[9];
    const float* W2r = (const float*)d_in[10];
    const float* W3l = (const float*)d_in[11];
    const float* b3  = (const float*)d_in[12];
    const float* W3r = (const float*)d_in[13];
    const float* Wlin1 = (const float*)d_in[14];
    const float* blin1 = (const float*)d_in[15];
    const float* Wlin2 = (const float*)d_in[16];
    const float* blin2 = (const float*)d_in[17];

    float* out = (float*)d_out;

    // ---- workspace layout ----
    char* p = (char*)d_ws;
    int* ghist = (int*)p;  p += 360 * 4;
    int* bb    = (int*)p;  p += 360 * 4;
    int* gcur  = (int*)p;  p += 360 * 4;
    int* entries = (int*)p; p += (size_t)NLIST * 4;
    int* rp    = (int*)p;  p += (size_t)(NTOT + 8) * 4;
    int* list  = (int*)p;  p += (size_t)NLIST * 4;
    float* c1  = (float*)p; p += 128 * 4;
    unsigned short* wb = (unsigned short*)p; p += (size_t)CVT_TOT * 2;
    unsigned short* W1l_b  = wb;
    unsigned short* W2l_b  = wb + 8192;
    unsigned short* W2r_b  = wb + 24576;
    unsigned short* W3l_b  = wb + 32768;
    unsigned short* W3r_b  = wb + 49152;
    unsigned short* Wlin1_b= wb + 65536;
    unsigned short* Wlin2_b= wb + 73728;
    unsigned short* mxb    = wb + 81920;                              // [NM][64]
    unsigned short* mean1  = (unsigned short*)p; p += (size_t)NU * FEAT * 2;
    unsigned short* user_x = (unsigned short*)p; p += (size_t)NU * HID * 2;
    unsigned short* mean2  = (unsigned short*)p; p += (size_t)NM * HID * 2;
    unsigned short* movie_z= (unsigned short*)p; p += (size_t)NM * HID * 2;
    unsigned short* Y3     = (unsigned short*)p; p += (size_t)NM * HID * 2;
    unsigned short* S3     = (unsigned short*)p; p += (size_t)NU * HID * 2;

    // ---- CSR build (misc fused into hist pass) ----
    hipMemsetAsync(ghist, 0, NBUCK * sizeof(int), stream);
    k_hist_misc<<<NPBLK + CVT_BLKS + IDX_BLKS + 1, 256, 0, stream>>>(
        user_idx, movie_idx, ghist,
        W1l, W2l, W2r, W3l, W3r, Wlin1, Wlin2, movie_x, wb,
        tuples, out + (size_t)(NU + NM) * OUTD, user_emb, W1r, b1, c1);
    k_bscan<<<1, 512, 0, stream>>>(ghist, bb, gcur);
    k_part<<<NPBLK, 256, 0, stream>>>(user_idx, movie_idx, gcur, entries);
    k_csr<<<NBUCK, 256, 0, stream>>>(bb, entries, rp, list);

    // ---- conv1: gather (high-TLP) + GEMM -> user_x ----
    k_gather_b<FEAT><<<(NU + 31) / 32, 256, 0, stream>>>(mxb, rp, list, mean1, 0, NU);
    k_mf2<FEAT, HID, true, true, false><<<(NU + 127) / 128, 256, 0, stream>>>(
        mean1, W1l_b, c1, user_x, NU);

    // ---- conv2 + lin2 + Y3 projection (fused movie chain) ----
    k_gather_b<HID><<<(NM + 15) / 16, 256, 0, stream>>>(user_x, rp, list, mean2, NU, NM);
    k_fused_m<<<(NM + 127) / 128, 256, 0, stream>>>(
        mean2, mxb, W2l_b, W2r_b, b2, movie_z, Wlin2_b, blin2, W3l_b, Y3,
        out + (size_t)NU * OUTD, NM);

    // ---- conv3 + lin1: gather Y3 -> S3; slim fused user chain ----
    k_gather_b<HID><<<(NU + 15) / 16, 256, 0, stream>>>(Y3, rp, list, S3, 0, NU);
    k_fused_u<<<(NU + 127) / 128, 256, 0, stream>>>(
        S3, user_x, W3r_b, b3, Wlin1_b, blin1, out, NU);
}

// Round 11
// 166.756 us; speedup vs baseline: 1.8188x; 1.0030x over previous
//
#include <hip/hip_runtime.h>

typedef __attribute__((ext_vector_type(8))) short short8;   // 8 bf16 (4 VGPR)
typedef __attribute__((ext_vector_type(4))) float f32x4;    // MFMA acc

static const int NU = 100000;
static const int NM = 20000;
static const int NE = 600000;
static const int FEAT = 64;
static const int HID = 128;
static const int OUTD = 64;
static const int NTOT = NU + NM;
static const int NLIST = 2 * NE;
static const int CVT_TOT = 81920 + NM * FEAT;   // weights + movie_x
static const int CVT_BLKS = (CVT_TOT + 255) / 256;
static const int IDX_BLKS = (100000 + 255) / 256;

// bucket geometry: users 512 nodes/bucket, movies 128 nodes/bucket
static const int UB_SHIFT = 9;
static const int MB_SHIFT = 7;
static const int NBU = (NU + 511) >> 9;           // 196
static const int NBM = (NM + 127) >> 7;           // 157
static const int NBUCK = NBU + NBM;               // 353
static const int EPB = 4096;
static const int NPBLK = (NE + EPB - 1) / EPB;    // 147

__device__ inline float b2f(unsigned short h) {
    unsigned int u = ((unsigned int)h) << 16;
    float f; __builtin_memcpy(&f, &u, 4); return f;
}
__device__ inline unsigned short f2b(float f) {
    unsigned int u; __builtin_memcpy(&u, &f, 4);
    u += 0x7FFFu + ((u >> 16) & 1u);            // RNE
    return (unsigned short)(u >> 16);
}
__device__ inline unsigned int pk2(float a, float b) {
    return (unsigned int)f2b(a) | ((unsigned int)f2b(b) << 16);
}
// XOR swizzle within a row: spreads 16B frag slots across banks (G4)
__device__ inline int wswz(int row, int bc, int rowbytes) {
    return row * rowbytes + (bc ^ ((row & 7) << 4));
}

// ---------------- pass 1 merged: bucket histogram + cvt + new_index + c1 ----------------
__global__ __launch_bounds__(256) void k_hist_misc(
        const int* __restrict__ ui, const int* __restrict__ mi, int* __restrict__ ghist,
        const float* __restrict__ w1l, const float* __restrict__ w2l,
        const float* __restrict__ w2r, const float* __restrict__ w3l,
        const float* __restrict__ w3r, const float* __restrict__ wl1,
        const float* __restrict__ wl2, const float* __restrict__ mx,
        unsigned short* __restrict__ dst,
        const int* __restrict__ tpl, float* __restrict__ oidx,
        const float* __restrict__ ue, const float* __restrict__ w1r,
        const float* __restrict__ b1, float* __restrict__ c1) {
    __shared__ int h[NBUCK];
    const int b = blockIdx.x;
    const int tid = threadIdx.x;
    if (b < NPBLK) {
        for (int i = tid; i < NBUCK; i += 256) h[i] = 0;
        __syncthreads();
#pragma unroll
        for (int it = 0; it < EPB / 256; ++it) {
            int e = b * EPB + it * 256 + tid;
            if (e < NE) {
                atomicAdd(&h[ui[e] >> UB_SHIFT], 1);
                atomicAdd(&h[NBU + (mi[e] >> MB_SHIFT)], 1);
            }
        }
        __syncthreads();
        for (int i = tid; i < NBUCK; i += 256)
            if (h[i]) atomicAdd(&ghist[i], h[i]);
    } else if (b < NPBLK + CVT_BLKS) {
        int g = (b - NPBLK) * 256 + tid;
        if (g >= CVT_TOT) return;
        const float* s; int o;
        if      (g < 8192)   { s = w1l; o = g; }
        else if (g < 24576)  { s = w2l; o = g - 8192; }
        else if (g < 32768)  { s = w2r; o = g - 24576; }
        else if (g < 49152)  { s = w3l; o = g - 32768; }
        else if (g < 65536)  { s = w3r; o = g - 49152; }
        else if (g < 73728)  { s = wl1; o = g - 65536; }
        else if (g < 81920)  { s = wl2; o = g - 73728; }
        else                 { s = mx;  o = g - 81920; }
        dst[g] = f2b(s[o]);
    } else if (b < NPBLK + CVT_BLKS + IDX_BLKS) {
        int i = (b - NPBLK - CVT_BLKS) * 256 + tid;
        if (i < 100000) {
            oidx[i] = (float)tpl[i];
            oidx[100000 + i] = (float)(tpl[100000 + i] + NU);
        }
    } else {
        int hh = tid;
        if (hh < HID) {
            float a = 0.f;
#pragma unroll 16
            for (int k = 0; k < HID; ++k) a += ue[k] * w1r[hh * HID + k];
            c1[hh] = a + b1[hh];
        }
    }
}

__global__ __launch_bounds__(512) void k_bscan(const int* __restrict__ ghist,
                                               int* __restrict__ bb,
                                               int* __restrict__ gcur) {
    __shared__ int s[512];
    const int tid = threadIdx.x;
    int v = (tid < NBUCK) ? ghist[tid] : 0;
    s[tid] = v;
    __syncthreads();
#pragma unroll
    for (int off = 1; off < 512; off <<= 1) {
        int x = (tid >= off) ? s[tid - off] : 0;
        __syncthreads();
        s[tid] += x;
        __syncthreads();
    }
    int excl = s[tid] - v;
    if (tid < NBUCK) { bb[tid] = excl; gcur[tid] = excl; }
    if (tid == 511) bb[NBUCK] = s[511];
}

__global__ __launch_bounds__(256) void k_part(const int* __restrict__ ui,
                                              const int* __restrict__ mi,
                                              int* __restrict__ gcur,
                                              int* __restrict__ entries) {
    __shared__ int h[NBUCK], base[NBUCK], cur[NBUCK];
    const int tid = threadIdx.x;
    for (int i = tid; i < NBUCK; i += 256) h[i] = 0;
    __syncthreads();

    int eu[EPB / 256], em[EPB / 256];
#pragma unroll
    for (int it = 0; it < EPB / 256; ++it) {
        int e = blockIdx.x * EPB + it * 256 + tid;
        if (e < NE) {
            eu[it] = ui[e]; em[it] = mi[e];
            atomicAdd(&h[eu[it] >> UB_SHIFT], 1);
            atomicAdd(&h[NBU + (em[it] >> MB_SHIFT)], 1);
        } else eu[it] = -1;
    }
    __syncthreads();
    for (int i = tid; i < NBUCK; i += 256) {
        int c = h[i];
        base[i] = c ? atomicAdd(&gcur[i], c) : 0;
        cur[i] = 0;
    }
    __syncthreads();
#pragma unroll
    for (int it = 0; it < EPB / 256; ++it) {
        if (eu[it] < 0) continue;
        int u = eu[it], m = em[it];
        int bu = u >> UB_SHIFT;
        int o1 = base[bu] + atomicAdd(&cur[bu], 1);
        entries[o1] = (m << UB_SHIFT) | (u & 511);
        int bm = NBU + (m >> MB_SHIFT);
        int o2 = base[bm] + atomicAdd(&cur[bm], 1);
        entries[o2] = (u << MB_SHIFT) | (m & 127);
    }
}

__global__ __launch_bounds__(256) void k_csr(const int* __restrict__ bb,
                                             const int* __restrict__ entries,
                                             int* __restrict__ rp,
                                             int* __restrict__ list) {
    __shared__ int lcnt[512], lrp[512], lcur[512], ps[256];
    const int b = blockIdx.x;
    const int tid = threadIdx.x;
    const int s = bb[b], e = bb[b + 1];
    const bool isU = b < NBU;
    const int shift = isU ? UB_SHIFT : MB_SHIFT;
    const int mask = isU ? 511 : 127;
    const int n0 = isU ? (b << UB_SHIFT) : ((b - NBU) << MB_SHIFT);
    const int nNodes = isU ? min(512, NU - n0) : min(128, NM - n0);
    const int g0 = isU ? n0 : NU + n0;

    for (int i = tid; i < 512; i += 256) { lcnt[i] = 0; lcur[i] = 0; }
    __syncthreads();
    for (int i = s + tid; i < e; i += 256)
        atomicAdd(&lcnt[entries[i] & mask], 1);
    __syncthreads();
    int a0 = lcnt[2 * tid], a1 = lcnt[2 * tid + 1];
    int pr = a0 + a1;
    ps[tid] = pr;
    __syncthreads();
#pragma unroll
    for (int off = 1; off < 256; off <<= 1) {
        int x = (tid >= off) ? ps[tid - off] : 0;
        __syncthreads();
        ps[tid] += x;
        __syncthreads();
    }
    int excl = ps[tid] - pr;
    lrp[2 * tid] = excl;
    lrp[2 * tid + 1] = excl + a0;
    __syncthreads();
    for (int i = tid; i < nNodes; i += 256) rp[g0 + i] = s + lrp[i];
    if (b == NBUCK - 1 && tid == 0) rp[NTOT] = e;
    for (int i = s + tid; i < e; i += 256) {
        int p = entries[i];
        int dl = p & mask;
        int off = s + lrp[dl] + atomicAdd(&lcur[dl], 1);
        list[off] = p >> shift;
    }
}

// ---------------- bf16 gather-based segment mean (high-TLP, standalone) ----------------
template<int C>
__global__ __launch_bounds__(256) void k_gather_b(const unsigned short* __restrict__ src,
                                                  const int* __restrict__ rp,
                                                  const int* __restrict__ list,
                                                  unsigned short* __restrict__ dst,
                                                  int base, int n) {
    constexpr int TPN = C / 8;
    constexpr int NPB = 256 / TPN;
    const int node = blockIdx.x * NPB + threadIdx.x / TPN;
    if (node >= n) return;
    const int c8 = (threadIdx.x % TPN) * 8;
    const int g = base + node;
    const int s = rp[g], e = rp[g + 1];

    float a[8];
#pragma unroll
    for (int j = 0; j < 8; ++j) a[j] = 0.f;

    int i = s;
    for (; i + 1 < e; i += 2) {
        int r0 = list[i], r1 = list[i + 1];
        short8 v0 = *reinterpret_cast<const short8*>(src + (size_t)r0 * C + c8);
        short8 v1 = *reinterpret_cast<const short8*>(src + (size_t)r1 * C + c8);
#pragma unroll
        for (int j = 0; j < 8; ++j)
            a[j] += b2f((unsigned short)v0[j]) + b2f((unsigned short)v1[j]);
    }
    if (i < e) {
        int r0 = list[i];
        short8 v0 = *reinterpret_cast<const short8*>(src + (size_t)r0 * C + c8);
#pragma unroll
        for (int j = 0; j < 8; ++j) a[j] += b2f((unsigned short)v0[j]);
    }
    const float sc = 1.0f / (float)max(e - s, 1);
    short8 o;
#pragma unroll
    for (int j = 0; j < 8; ++j) o[j] = (short)f2b(a[j] * sc);
    *reinterpret_cast<short8*>(dst + (size_t)node * C + c8) = o;
}

// ---------------- gather + mean + c1 + relu epilogue (conv1 push-through) ----------------
// user_x[node] = relu( mean(Y1[neighbors]) + c1 )
__global__ __launch_bounds__(256) void k_gather_relu(const unsigned short* __restrict__ Y1,
                                                     const int* __restrict__ rp,
                                                     const int* __restrict__ list,
                                                     const float* __restrict__ c1,
                                                     unsigned short* __restrict__ user_x,
                                                     int n) {
    const int node = blockIdx.x * 16 + threadIdx.x / 16;
    if (node >= n) return;
    const int c8 = (threadIdx.x % 16) * 8;
    const int s = rp[node], e = rp[node + 1];

    float a[8];
#pragma unroll
    for (int j = 0; j < 8; ++j) a[j] = 0.f;

    int i = s;
    for (; i + 1 < e; i += 2) {
        int r0 = list[i], r1 = list[i + 1];
        short8 v0 = *reinterpret_cast<const short8*>(Y1 + (size_t)r0 * HID + c8);
        short8 v1 = *reinterpret_cast<const short8*>(Y1 + (size_t)r1 * HID + c8);
#pragma unroll
        for (int j = 0; j < 8; ++j)
            a[j] += b2f((unsigned short)v0[j]) + b2f((unsigned short)v1[j]);
    }
    if (i < e) {
        int r0 = list[i];
        short8 v0 = *reinterpret_cast<const short8*>(Y1 + (size_t)r0 * HID + c8);
#pragma unroll
        for (int j = 0; j < 8; ++j) a[j] += b2f((unsigned short)v0[j]);
    }
    const float sc = 1.0f / (float)max(e - s, 1);
    float4 cv0 = *reinterpret_cast<const float4*>(c1 + c8);
    float4 cv1 = *reinterpret_cast<const float4*>(c1 + c8 + 4);
    float r[8];
    r[0] = fmaxf(a[0] * sc + cv0.x, 0.f); r[1] = fmaxf(a[1] * sc + cv0.y, 0.f);
    r[2] = fmaxf(a[2] * sc + cv0.z, 0.f); r[3] = fmaxf(a[3] * sc + cv0.w, 0.f);
    r[4] = fmaxf(a[4] * sc + cv1.x, 0.f); r[5] = fmaxf(a[5] * sc + cv1.y, 0.f);
    r[6] = fmaxf(a[6] * sc + cv1.z, 0.f); r[7] = fmaxf(a[7] * sc + cv1.w, 0.f);
    uint4 o;
    o.x = pk2(r[0], r[1]); o.y = pk2(r[2], r[3]);
    o.z = pk2(r[4], r[5]); o.w = pk2(r[6], r[7]);
    *reinterpret_cast<uint4*>(user_x + (size_t)node * HID + c8) = o;
}

// ================= swapped-operand MFMA GEMM, W staged in LDS =================
template<int K, int NO, bool AVEC, bool RELU, bool F32OUT>
__global__ __launch_bounds__(256) void k_mf2(const unsigned short* __restrict__ X,
                                             const unsigned short* __restrict__ W,
                                             const float* __restrict__ vec,
                                             void* __restrict__ Yv, int M) {
    constexpr int KT = K / 32;
    constexpr int CG = NO / 16;
    constexpr int WB = NO * K * 2;
    constexpr int RB = K * 2;
    __shared__ __align__(16) char lds[WB];
    const int tid = threadIdx.x;
    const int lane = tid & 63;
    const int wv = tid >> 6;
    const int rbase = blockIdx.x * 128 + wv * 32;
    const int lr = lane & 15;
    const int kg = lane >> 4;

#pragma unroll
    for (int i = 0; i < WB / 16 / 256; ++i) {
        int idx = tid + i * 256;
        int row = idx / (RB / 16);
        int bc = (idx % (RB / 16)) * 16;
        *reinterpret_cast<uint4*>(lds + wswz(row, bc, RB)) =
            *reinterpret_cast<const uint4*>((const char*)W + idx * 16);
    }

    short8 xb[2][KT];
#pragma unroll
    for (int t = 0; t < 2; ++t) {
        int row = min(rbase + t * 16 + lr, M - 1);
#pragma unroll
        for (int kt = 0; kt < KT; ++kt)
            xb[t][kt] = *reinterpret_cast<const short8*>(
                X + (size_t)row * K + kt * 32 + kg * 8);
    }
    __syncthreads();

    f32x4 acc[2][CG];
#pragma unroll
    for (int t = 0; t < 2; ++t)
#pragma unroll
        for (int c = 0; c < CG; ++c) acc[t][c] = (f32x4){0.f, 0.f, 0.f, 0.f};

#pragma unroll
    for (int cg = 0; cg < CG; ++cg) {
        short8 wf[KT];
#pragma unroll
        for (int kt = 0; kt < KT; ++kt)
            wf[kt] = *reinterpret_cast<const short8*>(
                lds + wswz(cg * 16 + lr, kt * 64 + kg * 16, RB));
#pragma unroll
        for (int kt = 0; kt < KT; ++kt)
#pragma unroll
            for (int t = 0; t < 2; ++t)
                acc[t][cg] = __builtin_amdgcn_mfma_f32_16x16x32_bf16(
                    wf[kt], xb[t][kt], acc[t][cg], 0, 0, 0);
    }

#pragma unroll
    for (int t = 0; t < 2; ++t) {
        const int u = rbase + t * 16 + lr;
        if (u >= M) continue;
#pragma unroll
        for (int cg = 0; cg < CG; ++cg) {
            const int h0 = cg * 16 + kg * 4;
            float v[4];
#pragma unroll
            for (int r = 0; r < 4; ++r) v[r] = acc[t][cg][r];
            if (AVEC) {
                float4 vv = *reinterpret_cast<const float4*>(vec + h0);
                v[0] += vv.x; v[1] += vv.y; v[2] += vv.z; v[3] += vv.w;
            }
            if (RELU)
#pragma unroll
                for (int r = 0; r < 4; ++r) v[r] = fmaxf(v[r], 0.f);
            if (F32OUT) {
                float4 o = make_float4(v[0], v[1], v[2], v[3]);
                *reinterpret_cast<float4*>((float*)Yv + (size_t)u * NO + h0) = o;
            } else {
                uint2 o = make_uint2(pk2(v[0], v[1]), pk2(v[2], v[3]));
                *reinterpret_cast<uint2*>((unsigned short*)Yv + (size_t)u * NO + h0) = o;
            }
        }
    }
}

// ================= fused user chain (slim: W3l pushed through mean as S3 carry) =================
// Z = relu(S3 + user_x@W3r^T + b3); out = Z@Wlin1^T + blin1
__global__ __launch_bounds__(256) void k_fused_u(
        const unsigned short* __restrict__ S3, const unsigned short* __restrict__ user_x,
        const unsigned short* __restrict__ W3r, const float* __restrict__ b3,
        const unsigned short* __restrict__ Wl1, const float* __restrict__ bl1,
        float* __restrict__ out, int M) {
    __shared__ __align__(16) char lds[49152];   // [0,32K) W3r -> Z; [32K,48K) Wl1 (upfront)
    const int tid = threadIdx.x;
    const int lane = tid & 63;
    const int wv = tid >> 6;
    const int rbase = blockIdx.x * 128 + wv * 32;
    const int lr = lane & 15;
    const int kg = lane >> 4;

    // stage W3r (32KB, 256B rows) + Wl1 (16KB, 256B rows)
#pragma unroll
    for (int i = 0; i < 8; ++i) {
        int idx = tid + i * 256;
        int row = idx >> 4, bc = (idx & 15) << 4;
        *reinterpret_cast<uint4*>(lds + wswz(row, bc, 256)) =
            *reinterpret_cast<const uint4*>((const char*)W3r + idx * 16);
    }
#pragma unroll
    for (int i = 0; i < 4; ++i) {
        int idx = tid + i * 256;
        int row = idx >> 4, bc = (idx & 15) << 4;
        *reinterpret_cast<uint4*>(lds + 32768 + wswz(row, bc, 256)) =
            *reinterpret_cast<const uint4*>((const char*)Wl1 + idx * 16);
    }

    short8 xc[2][4];
#pragma unroll
    for (int t = 0; t < 2; ++t) {
        int row = min(rbase + t * 16 + lr, M - 1);
#pragma unroll
        for (int kt = 0; kt < 4; ++kt)
            xc[t][kt] = *reinterpret_cast<const short8*>(
                user_x + (size_t)row * HID + kt * 32 + kg * 8);
    }
    __syncthreads();

    f32x4 acc[2][8];
#pragma unroll
    for (int t = 0; t < 2; ++t)
#pragma unroll
        for (int c = 0; c < 8; ++c) acc[t][c] = (f32x4){0.f, 0.f, 0.f, 0.f};

#pragma unroll
    for (int cg = 0; cg < 8; ++cg) {
        short8 wr[4];
#pragma unroll
        for (int kt = 0; kt < 4; ++kt)
            wr[kt] = *reinterpret_cast<const short8*>(
                lds + wswz(cg * 16 + lr, kt * 64 + kg * 16, 256));
#pragma unroll
        for (int kt = 0; kt < 4; ++kt)
#pragma unroll
            for (int t = 0; t < 2; ++t)
                acc[t][cg] = __builtin_amdgcn_mfma_f32_16x16x32_bf16(
                    wr[kt], xc[t][kt], acc[t][cg], 0, 0, 0);
    }
    __syncthreads();   // W3r reads done -> Z may overwrite

    // epilogue: Z = relu(acc + S3 + b3) -> swizzled LDS
#pragma unroll
    for (int t = 0; t < 2; ++t) {
        const int ul = wv * 32 + t * 16 + lr;
        const int u = min(rbase + t * 16 + lr, M - 1);
#pragma unroll
        for (int cg = 0; cg < 8; ++cg) {
            const int h0 = cg * 16 + kg * 4;
            uint2 s3 = *reinterpret_cast<const uint2*>(S3 + (size_t)u * HID + h0);
            float4 vv = *reinterpret_cast<const float4*>(b3 + h0);
            float v0 = fmaxf(acc[t][cg][0] + b2f((unsigned short)(s3.x & 0xffff)) + vv.x, 0.f);
            float v1 = fmaxf(acc[t][cg][1] + b2f((unsigned short)(s3.x >> 16)) + vv.y, 0.f);
            float v2 = fmaxf(acc[t][cg][2] + b2f((unsigned short)(s3.y & 0xffff)) + vv.z, 0.f);
            float v3 = fmaxf(acc[t][cg][3] + b2f((unsigned short)(s3.y >> 16)) + vv.w, 0.f);
            uint2 pk = make_uint2(pk2(v0, v1), pk2(v2, v3));
            *reinterpret_cast<uint2*>(lds + wswz(ul, h0 * 2, 256)) = pk;
        }
    }
    __syncthreads();

    // GEMM2: out = Z @ Wlin1^T + blin1
    short8 zb[2][4];
#pragma unroll
    for (int t = 0; t < 2; ++t) {
        const int ul = wv * 32 + t * 16 + lr;
#pragma unroll
        for (int kt = 0; kt < 4; ++kt)
            zb[t][kt] = *reinterpret_cast<const short8*>(
                lds + wswz(ul, kt * 64 + kg * 16, 256));
    }
    f32x4 a2[2][4];
#pragma unroll
    for (int t = 0; t < 2; ++t)
#pragma unroll
        for (int c = 0; c < 4; ++c) a2[t][c] = (f32x4){0.f, 0.f, 0.f, 0.f};
#pragma unroll
    for (int cg = 0; cg < 4; ++cg) {
        short8 wf[4];
#pragma unroll
        for (int kt = 0; kt < 4; ++kt)
            wf[kt] = *reinterpret_cast<const short8*>(
                lds + 32768 + wswz(cg * 16 + lr, kt * 64 + kg * 16, 256));
#pragma unroll
        for (int kt = 0; kt < 4; ++kt)
#pragma unroll
            for (int t = 0; t < 2; ++t)
                a2[t][cg] = __builtin_amdgcn_mfma_f32_16x16x32_bf16(
                    wf[kt], zb[t][kt], a2[t][cg], 0, 0, 0);
    }
#pragma unroll
    for (int t = 0; t < 2; ++t) {
        const int u = rbase + t * 16 + lr;
        if (u >= M) continue;
#pragma unroll
        for (int cg = 0; cg < 4; ++cg) {
            const int o0 = cg * 16 + kg * 4;
            float4 bb = *reinterpret_cast<const float4*>(bl1 + o0);
            float4 o = make_float4(a2[t][cg][0] + bb.x, a2[t][cg][1] + bb.y,
                                   a2[t][cg][2] + bb.z, a2[t][cg][3] + bb.w);
            *reinterpret_cast<float4*>(out + (size_t)u * OUTD + o0) = o;
        }
    }
}

// ================= fused movie chain + Y3 projection =================
// Z = relu(mean2@W2l^T + mxb@W2r^T + b2); movie_z = Z; out = Z@Wlin2^T + blin2;
// Y3 = Z @ W3l^T  (push-through for conv3)
__global__ __launch_bounds__(256) void k_fused_m(
        const unsigned short* __restrict__ mean2, const unsigned short* __restrict__ mxb,
        const unsigned short* __restrict__ W2l, const unsigned short* __restrict__ W2r,
        const float* __restrict__ b2, unsigned short* __restrict__ movie_z,
        const unsigned short* __restrict__ Wl2, const float* __restrict__ bl2,
        const unsigned short* __restrict__ W3l, unsigned short* __restrict__ Y3,
        float* __restrict__ out, int M) {
    __shared__ __align__(16) char lds[65536];
    // [0,32K) W2l -> Z; [32K,48K) W2r -> W3l(lo); [48K,64K) Wl2 -> W3l(hi)
    const int tid = threadIdx.x;
    const int lane = tid & 63;
    const int wv = tid >> 6;
    const int rbase = blockIdx.x * 128 + wv * 32;
    const int lr = lane & 15;
    const int kg = lane >> 4;

    // stage W2l (32KB, 256B rows), W2r (16KB, 128B rows), Wl2 (16KB, 256B rows)
#pragma unroll
    for (int i = 0; i < 8; ++i) {
        int idx = tid + i * 256;
        int row = idx >> 4, bc = (idx & 15) << 4;
        *reinterpret_cast<uint4*>(lds + wswz(row, bc, 256)) =
            *reinterpret_cast<const uint4*>((const char*)W2l + idx * 16);
    }
#pragma unroll
    for (int i = 0; i < 4; ++i) {
        int idx = tid + i * 256;
        int row = idx >> 3, bc = (idx & 7) << 4;
        *reinterpret_cast<uint4*>(lds + 32768 + wswz(row, bc, 128)) =
            *reinterpret_cast<const uint4*>((const char*)W2r + idx * 16);
        int row2 = idx >> 4, bc2 = (idx & 15) << 4;
        *reinterpret_cast<uint4*>(lds + 49152 + wswz(row2, bc2, 256)) =
            *reinterpret_cast<const uint4*>((const char*)Wl2 + idx * 16);
    }

    short8 xa[2][4], xc[2][2];
#pragma unroll
    for (int t = 0; t < 2; ++t) {
        int row = min(rbase + t * 16 + lr, M - 1);
#pragma unroll
        for (int kt = 0; kt < 4; ++kt)
            xa[t][kt] = *reinterpret_cast<const short8*>(
                mean2 + (size_t)row * HID + kt * 32 + kg * 8);
#pragma unroll
        for (int kt = 0; kt < 2; ++kt)
            xc[t][kt] = *reinterpret_cast<const short8*>(
                mxb + (size_t)row * FEAT + kt * 32 + kg * 8);
    }
    __syncthreads();

    f32x4 acc[2][8];
#pragma unroll
    for (int t = 0; t < 2; ++t)
#pragma unroll
        for (int c = 0; c < 8; ++c) acc[t][c] = (f32x4){0.f, 0.f, 0.f, 0.f};

#pragma unroll
    for (int cg = 0; cg < 8; ++cg) {
        short8 wl[4], wr[2];
#pragma unroll
        for (int kt = 0; kt < 4; ++kt)
            wl[kt] = *reinterpret_cast<const short8*>(
                lds + wswz(cg * 16 + lr, kt * 64 + kg * 16, 256));
#pragma unroll
        for (int kt = 0; kt < 2; ++kt)
            wr[kt] = *reinterpret_cast<const short8*>(
                lds + 32768 + wswz(cg * 16 + lr, kt * 64 + kg * 16, 128));
#pragma unroll
        for (int kt = 0; kt < 4; ++kt)
#pragma unroll
            for (int t = 0; t < 2; ++t)
                acc[t][cg] = __builtin_amdgcn_mfma_f32_16x16x32_bf16(
                    wl[kt], xa[t][kt], acc[t][cg], 0, 0, 0);
#pragma unroll
        for (int kt = 0; kt < 2; ++kt)
#pragma unroll
            for (int t = 0; t < 2; ++t)
                acc[t][cg] = __builtin_amdgcn_mfma_f32_16x16x32_bf16(
                    wr[kt], xc[t][kt], acc[t][cg], 0, 0, 0);
    }
    __syncthreads();   // W2l reads done -> Z may overwrite [0,32K)

    // epilogue 1: relu(acc + b2) -> Z (LDS) + global movie_z
#pragma unroll
    for (int t = 0; t < 2; ++t) {
        const int ul = wv * 32 + t * 16 + lr;
        const int u = rbase + t * 16 + lr;
#pragma unroll
        for (int cg = 0; cg < 8; ++cg) {
            const int h0 = cg * 16 + kg * 4;
            float4 vv = *reinterpret_cast<const float4*>(b2 + h0);
            float v0 = fmaxf(acc[t][cg][0] + vv.x, 0.f);
            float v1 = fmaxf(acc[t][cg][1] + vv.y, 0.f);
            float v2 = fmaxf(acc[t][cg][2] + vv.z, 0.f);
            float v3 = fmaxf(acc[t][cg][3] + vv.w, 0.f);
            uint2 pk = make_uint2(pk2(v0, v1), pk2(v2, v3));
            *reinterpret_cast<uint2*>(lds + wswz(ul, h0 * 2, 256)) = pk;
            if (u < M)
                *reinterpret_cast<uint2*>(movie_z + (size_t)u * HID + h0) = pk;
        }
    }
    __syncthreads();

    // GEMM2: out = Z @ Wlin2^T + blin2 (Z at [0,32K), Wl2 at [48K,64K))
    short8 zb[2][4];
#pragma unroll
    for (int t = 0; t < 2; ++t) {
        const int ul = wv * 32 + t * 16 + lr;
#pragma unroll
        for (int kt = 0; kt < 4; ++kt)
            zb[t][kt] = *reinterpret_cast<const short8*>(
                lds + wswz(ul, kt * 64 + kg * 16, 256));
    }
    f32x4 a2[2][4];
#pragma unroll
    for (int t = 0; t < 2; ++t)
#pragma unroll
        for (int c = 0; c < 4; ++c) a2[t][c] = (f32x4){0.f, 0.f, 0.f, 0.f};
#pragma unroll
    for (int cg = 0; cg < 4; ++cg) {
        short8 wf[4];
#pragma unroll
        for (int kt = 0; kt < 4; ++kt)
            wf[kt] = *reinterpret_cast<const short8*>(
                lds + 49152 + wswz(cg * 16 + lr, kt * 64 + kg * 16, 256));
#pragma unroll
        for (int kt = 0; kt < 4; ++kt)
#pragma unroll
            for (int t = 0; t < 2; ++t)
                a2[t][cg] = __builtin_amdgcn_mfma_f32_16x16x32_bf16(
                    wf[kt], zb[t][kt], a2[t][cg], 0, 0, 0);
    }
#pragma unroll
    for (int t = 0; t < 2; ++t) {
        const int u = rbase + t * 16 + lr;
        if (u >= M) continue;
#pragma unroll
        for (int cg = 0; cg < 4; ++cg) {
            const int o0 = cg * 16 + kg * 4;
            float4 bb = *reinterpret_cast<const float4*>(bl2 + o0);
            float4 o = make_float4(a2[t][cg][0] + bb.x, a2[t][cg][1] + bb.y,
                                   a2[t][cg][2] + bb.z, a2[t][cg][3] + bb.w);
            *reinterpret_cast<float4*>(out + (size_t)u * OUTD + o0) = o;
        }
    }
    __syncthreads();   // Wl2 + W2r reads done -> W3l may overwrite [32K,64K)

    // stage W3l (32KB, 256B rows) at [32K,64K)
#pragma unroll
    for (int i = 0; i < 8; ++i) {
        int idx = tid + i * 256;
        int row = idx >> 4, bc = (idx & 15) << 4;
        *reinterpret_cast<uint4*>(lds + 32768 + wswz(row, bc, 256)) =
            *reinterpret_cast<const uint4*>((const char*)W3l + idx * 16);
    }
    __syncthreads();

    // GEMM3: Y3 = Z @ W3l^T  (zb frags reused)
    f32x4 a3[2][8];
#pragma unroll
    for (int t = 0; t < 2; ++t)
#pragma unroll
        for (int c = 0; c < 8; ++c) a3[t][c] = (f32x4){0.f, 0.f, 0.f, 0.f};
#pragma unroll
    for (int cg = 0; cg < 8; ++cg) {
        short8 wf[4];
#pragma unroll
        for (int kt = 0; kt < 4; ++kt)
            wf[kt] = *reinterpret_cast<const short8*>(
                lds + 32768 + wswz(cg * 16 + lr, kt * 64 + kg * 16, 256));
#pragma unroll
        for (int kt = 0; kt < 4; ++kt)
#pragma unroll
            for (int t = 0; t < 2; ++t)
                a3[t][cg] = __builtin_amdgcn_mfma_f32_16x16x32_bf16(
                    wf[kt], zb[t][kt], a3[t][cg], 0, 0, 0);
    }
#pragma unroll
    for (int t = 0; t < 2; ++t) {
        const int u = rbase + t * 16 + lr;
        if (u >= M) continue;
#pragma unroll
        for (int cg = 0; cg < 8; ++cg) {
            const int h0 = cg * 16 + kg * 4;
            uint2 pk = make_uint2(pk2(a3[t][cg][0], a3[t][cg][1]),
                                  pk2(a3[t][cg][2], a3[t][cg][3]));
            *reinterpret_cast<uint2*>(Y3 + (size_t)u * HID + h0) = pk;
        }
    }
}

extern "C" void kernel_launch(void* const* d_in, const int* in_sizes, int n_in,
                              void* d_out, int out_size, void* d_ws, size_t ws_size,
                              hipStream_t stream) {
    const float* movie_x  = (const float*)d_in[0];
    const int*   user_idx = (const int*)d_in[1];
    const int*   movie_idx= (const int*)d_in[2];
    const int*   tuples   = (const int*)d_in[3];
    const float* user_emb = (const float*)d_in[4];
    const float* W1l = (const float*)d_in[5];
    const float* b1  = (const float*)d_in[6];
    const float* W1r = (const float*)d_in[7];
    const float* W2l = (const float*)d_in[8];
    const float* b2  = (const float*)d_in[9];
    const float* W2r = (const float*)d_in[10];
    const float* W3l = (const float*)d_in[11];
    const float* b3  = (const float*)d_in[12];
    const float* W3r = (const float*)d_in[13];
    const float* Wlin1 = (const float*)d_in[14];
    const float* blin1 = (const float*)d_in[15];
    const float* Wlin2 = (const float*)d_in[16];
    const float* blin2 = (const float*)d_in[17];

    float* out = (float*)d_out;

    // ---- workspace layout ----
    char* p = (char*)d_ws;
    int* ghist = (int*)p;  p += 360 * 4;
    int* bb    = (int*)p;  p += 360 * 4;
    int* gcur  = (int*)p;  p += 360 * 4;
    int* entries = (int*)p; p += (size_t)NLIST * 4;
    int* rp    = (int*)p;  p += (size_t)(NTOT + 8) * 4;
    int* list  = (int*)p;  p += (size_t)NLIST * 4;
    float* c1  = (float*)p; p += 128 * 4;
    unsigned short* wb = (unsigned short*)p; p += (size_t)CVT_TOT * 2;
    unsigned short* W1l_b  = wb;
    unsigned short* W2l_b  = wb + 8192;
    unsigned short* W2r_b  = wb + 24576;
    unsigned short* W3l_b  = wb + 32768;
    unsigned short* W3r_b  = wb + 49152;
    unsigned short* Wlin1_b= wb + 65536;
    unsigned short* Wlin2_b= wb + 73728;
    unsigned short* mxb    = wb + 81920;                              // [NM][64]
    unsigned short* Y1     = (unsigned short*)p; p += (size_t)NM * HID * 2;
    unsigned short* user_x = (unsigned short*)p; p += (size_t)NU * HID * 2;
    unsigned short* mean2  = (unsigned short*)p; p += (size_t)NM * HID * 2;
    unsigned short* movie_z= (unsigned short*)p; p += (size_t)NM * HID * 2;
    unsigned short* Y3     = (unsigned short*)p; p += (size_t)NM * HID * 2;
    unsigned short* S3     = (unsigned short*)p; p += (size_t)NU * HID * 2;

    // ---- CSR build (misc fused into hist pass) ----
    hipMemsetAsync(ghist, 0, NBUCK * sizeof(int), stream);
    k_hist_misc<<<NPBLK + CVT_BLKS + IDX_BLKS + 1, 256, 0, stream>>>(
        user_idx, movie_idx, ghist,
        W1l, W2l, W2r, W3l, W3r, Wlin1, Wlin2, movie_x, wb,
        tuples, out + (size_t)(NU + NM) * OUTD, user_emb, W1r, b1, c1);
    // Y1 = movie_x @ W1l^T  (conv1 push-through; tiny NM-scale GEMM)
    k_mf2<FEAT, HID, false, false, false><<<(NM + 127) / 128, 256, 0, stream>>>(
        mxb, W1l_b, nullptr, Y1, NM);
    k_bscan<<<1, 512, 0, stream>>>(ghist, bb, gcur);
    k_part<<<NPBLK, 256, 0, stream>>>(user_idx, movie_idx, gcur, entries);
    k_csr<<<NBUCK, 256, 0, stream>>>(bb, entries, rp, list);

    // ---- conv1: gather(Y1) + c1 + relu -> user_x (no NU-scale GEMM) ----
    k_gather_relu<<<(NU + 15) / 16, 256, 0, stream>>>(Y1, rp, list, c1, user_x, NU);

    // ---- conv2 + lin2 + Y3 projection (fused movie chain) ----
    k_gather_b<HID><<<(NM + 15) / 16, 256, 0, stream>>>(user_x, rp, list, mean2, NU, NM);
    k_fused_m<<<(NM + 127) / 128, 256, 0, stream>>>(
        mean2, mxb, W2l_b, W2r_b, b2, movie_z, Wlin2_b, blin2, W3l_b, Y3,
        out + (size_t)NU * OUTD, NM);

    // ---- conv3 + lin1: gather Y3 -> S3; slim fused user chain ----
    k_gather_b<HID><<<(NU + 15) / 16, 256, 0, stream>>>(Y3, rp, list, S3, 0, NU);
    k_fused_u<<<(NU + 127) / 128, 256, 0, stream>>>(
        S3, user_x, W3r_b, b3, Wlin1_b, blin1, out, NU);
}

// Round 12
// 164.226 us; speedup vs baseline: 1.8468x; 1.0154x over previous
//
#include <hip/hip_runtime.h>

typedef __attribute__((ext_vector_type(8))) short short8;   // 8 bf16 (4 VGPR)
typedef __attribute__((ext_vector_type(4))) float f32x4;    // MFMA acc

static const int NU = 100000;
static const int NM = 20000;
static const int NE = 600000;
static const int FEAT = 64;
static const int HID = 128;
static const int OUTD = 64;
static const int NTOT = NU + NM;
static const int CVT_TOT = 81920 + NM * FEAT;   // weights + movie_x
static const int CVT_BLKS = (CVT_TOT + 255) / 256;
static const int IDX_BLKS = (100000 + 255) / 256;

// bucket geometry: users 512 nodes/bucket, movies 128 nodes/bucket
static const int UB_SHIFT = 9;
static const int MB_SHIFT = 7;
static const int NBU = (NU + 511) >> 9;           // 196
static const int NBM = (NM + 127) >> 7;           // 157
static const int NBUCK = NBU + NBM;               // 353
static const int EPB = 4096;
static const int NPBLK = (NE + EPB - 1) / EPB;    // 147
// fixed bucket capacity: mean bucket ~3.1-3.8k, binomial sigma ~60 -> 8192 is 2x headroom
static const int CAP = 8192;

__device__ inline float b2f(unsigned short h) {
    unsigned int u = ((unsigned int)h) << 16;
    float f; __builtin_memcpy(&f, &u, 4); return f;
}
__device__ inline unsigned short f2b(float f) {
    unsigned int u; __builtin_memcpy(&u, &f, 4);
    u += 0x7FFFu + ((u >> 16) & 1u);            // RNE
    return (unsigned short)(u >> 16);
}
__device__ inline unsigned int pk2(float a, float b) {
    return (unsigned int)f2b(a) | ((unsigned int)f2b(b) << 16);
}
// XOR swizzle within a row: spreads 16B frag slots across banks (G4)
__device__ inline int wswz(int row, int bc, int rowbytes) {
    return row * rowbytes + (bc ^ ((row & 7) << 4));
}

// ---------------- pass 1 merged: edge partition (fixed-cap buckets) + cvt + idx + c1 ----------------
__global__ __launch_bounds__(256) void k_part_misc(
        const int* __restrict__ ui, const int* __restrict__ mi,
        int* __restrict__ gcur, int* __restrict__ entries,
        const float* __restrict__ w1l, const float* __restrict__ w2l,
        const float* __restrict__ w2r, const float* __restrict__ w3l,
        const float* __restrict__ w3r, const float* __restrict__ wl1,
        const float* __restrict__ wl2, const float* __restrict__ mx,
        unsigned short* __restrict__ dst,
        const int* __restrict__ tpl, float* __restrict__ oidx,
        const float* __restrict__ ue, const float* __restrict__ w1r,
        const float* __restrict__ b1, float* __restrict__ c1) {
    __shared__ int h[NBUCK], base[NBUCK], cur[NBUCK];
    const int b = blockIdx.x;
    const int tid = threadIdx.x;
    if (b < NPBLK) {
        for (int i = tid; i < NBUCK; i += 256) h[i] = 0;
        __syncthreads();
        int eu[EPB / 256], em[EPB / 256];
#pragma unroll
        for (int it = 0; it < EPB / 256; ++it) {
            int e = b * EPB + it * 256 + tid;
            if (e < NE) {
                eu[it] = ui[e]; em[it] = mi[e];
                atomicAdd(&h[eu[it] >> UB_SHIFT], 1);
                atomicAdd(&h[NBU + (em[it] >> MB_SHIFT)], 1);
            } else eu[it] = -1;
        }
        __syncthreads();
        for (int i = tid; i < NBUCK; i += 256) {
            int c = h[i];
            base[i] = c ? (i * CAP + atomicAdd(&gcur[i], c)) : 0;
            cur[i] = 0;
        }
        __syncthreads();
#pragma unroll
        for (int it = 0; it < EPB / 256; ++it) {
            if (eu[it] < 0) continue;
            int u = eu[it], m = em[it];
            int bu = u >> UB_SHIFT;
            int o1 = base[bu] + atomicAdd(&cur[bu], 1);
            entries[o1] = (m << UB_SHIFT) | (u & 511);
            int bm = NBU + (m >> MB_SHIFT);
            int o2 = base[bm] + atomicAdd(&cur[bm], 1);
            entries[o2] = (u << MB_SHIFT) | (m & 127);
        }
    } else if (b < NPBLK + CVT_BLKS) {
        int g = (b - NPBLK) * 256 + tid;
        if (g >= CVT_TOT) return;
        const float* s; int o;
        if      (g < 8192)   { s = w1l; o = g; }
        else if (g < 24576)  { s = w2l; o = g - 8192; }
        else if (g < 32768)  { s = w2r; o = g - 24576; }
        else if (g < 49152)  { s = w3l; o = g - 32768; }
        else if (g < 65536)  { s = w3r; o = g - 49152; }
        else if (g < 73728)  { s = wl1; o = g - 65536; }
        else if (g < 81920)  { s = wl2; o = g - 73728; }
        else                 { s = mx;  o = g - 81920; }
        dst[g] = f2b(s[o]);
    } else if (b < NPBLK + CVT_BLKS + IDX_BLKS) {
        int i = (b - NPBLK - CVT_BLKS) * 256 + tid;
        if (i < 100000) {
            oidx[i] = (float)tpl[i];
            oidx[100000 + i] = (float)(tpl[100000 + i] + NU);
        }
    } else {
        int hh = tid;
        if (hh < HID) {
            float a = 0.f;
#pragma unroll 16
            for (int k = 0; k < HID; ++k) a += ue[k] * w1r[hh * HID + k];
            c1[hh] = a + b1[hh];
        }
    }
}

// ---------------- pass 2: per-bucket CSR build in LDS (rp2 = (start,end) per node) ----------------
__global__ __launch_bounds__(256) void k_csr(const int* __restrict__ gcur,
                                             const int* __restrict__ entries,
                                             int2* __restrict__ rp2,
                                             int* __restrict__ list) {
    __shared__ int lcnt[512], lrp[512], lcur[512], ps[256];
    const int b = blockIdx.x;
    const int tid = threadIdx.x;
    const int s = b * CAP;
    const int e = s + gcur[b];
    const bool isU = b < NBU;
    const int shift = isU ? UB_SHIFT : MB_SHIFT;
    const int mask = isU ? 511 : 127;
    const int n0 = isU ? (b << UB_SHIFT) : ((b - NBU) << MB_SHIFT);
    const int nNodes = isU ? min(512, NU - n0) : min(128, NM - n0);
    const int g0 = isU ? n0 : NU + n0;

    for (int i = tid; i < 512; i += 256) { lcnt[i] = 0; lcur[i] = 0; }
    __syncthreads();
    for (int i = s + tid; i < e; i += 256)
        atomicAdd(&lcnt[entries[i] & mask], 1);
    __syncthreads();
    int a0 = lcnt[2 * tid], a1 = lcnt[2 * tid + 1];
    int pr = a0 + a1;
    ps[tid] = pr;
    __syncthreads();
#pragma unroll
    for (int off = 1; off < 256; off <<= 1) {
        int x = (tid >= off) ? ps[tid - off] : 0;
        __syncthreads();
        ps[tid] += x;
        __syncthreads();
    }
    int excl = ps[tid] - pr;
    lrp[2 * tid] = excl;
    lrp[2 * tid + 1] = excl + a0;
    __syncthreads();
    for (int i = tid; i < nNodes; i += 256)
        rp2[g0 + i] = make_int2(s + lrp[i], s + lrp[i] + lcnt[i]);
    for (int i = s + tid; i < e; i += 256) {
        int p = entries[i];
        int dl = p & mask;
        int off = s + lrp[dl] + atomicAdd(&lcur[dl], 1);
        list[off] = p >> shift;
    }
}

// ---------------- bf16 gather-based segment mean (4-edge unrolled) ----------------
template<int C>
__global__ __launch_bounds__(256) void k_gather_b(const unsigned short* __restrict__ src,
                                                  const int2* __restrict__ rp2,
                                                  const int* __restrict__ list,
                                                  unsigned short* __restrict__ dst,
                                                  int base, int n) {
    constexpr int TPN = C / 8;
    constexpr int NPB = 256 / TPN;
    const int node = blockIdx.x * NPB + threadIdx.x / TPN;
    if (node >= n) return;
    const int c8 = (threadIdx.x % TPN) * 8;
    const int2 se = rp2[base + node];
    const int s = se.x, e = se.y;

    float a[8];
#pragma unroll
    for (int j = 0; j < 8; ++j) a[j] = 0.f;

    int i = s;
    for (; i + 3 < e; i += 4) {
        int r0 = list[i], r1 = list[i + 1], r2 = list[i + 2], r3 = list[i + 3];
        short8 v0 = *reinterpret_cast<const short8*>(src + (size_t)r0 * C + c8);
        short8 v1 = *reinterpret_cast<const short8*>(src + (size_t)r1 * C + c8);
        short8 v2 = *reinterpret_cast<const short8*>(src + (size_t)r2 * C + c8);
        short8 v3 = *reinterpret_cast<const short8*>(src + (size_t)r3 * C + c8);
#pragma unroll
        for (int j = 0; j < 8; ++j)
            a[j] += (b2f((unsigned short)v0[j]) + b2f((unsigned short)v1[j]))
                  + (b2f((unsigned short)v2[j]) + b2f((unsigned short)v3[j]));
    }
    for (; i < e; ++i) {
        int r0 = list[i];
        short8 v0 = *reinterpret_cast<const short8*>(src + (size_t)r0 * C + c8);
#pragma unroll
        for (int j = 0; j < 8; ++j) a[j] += b2f((unsigned short)v0[j]);
    }
    const float sc = 1.0f / (float)max(e - s, 1);
    short8 o;
#pragma unroll
    for (int j = 0; j < 8; ++j) o[j] = (short)f2b(a[j] * sc);
    *reinterpret_cast<short8*>(dst + (size_t)node * C + c8) = o;
}

// ---------------- gather + mean + c1 + relu epilogue (conv1 push-through) ----------------
__global__ __launch_bounds__(256) void k_gather_relu(const unsigned short* __restrict__ Y1,
                                                     const int2* __restrict__ rp2,
                                                     const int* __restrict__ list,
                                                     const float* __restrict__ c1,
                                                     unsigned short* __restrict__ user_x,
                                                     int n) {
    const int node = blockIdx.x * 16 + threadIdx.x / 16;
    if (node >= n) return;
    const int c8 = (threadIdx.x % 16) * 8;
    const int2 se = rp2[node];
    const int s = se.x, e = se.y;

    float a[8];
#pragma unroll
    for (int j = 0; j < 8; ++j) a[j] = 0.f;

    int i = s;
    for (; i + 3 < e; i += 4) {
        int r0 = list[i], r1 = list[i + 1], r2 = list[i + 2], r3 = list[i + 3];
        short8 v0 = *reinterpret_cast<const short8*>(Y1 + (size_t)r0 * HID + c8);
        short8 v1 = *reinterpret_cast<const short8*>(Y1 + (size_t)r1 * HID + c8);
        short8 v2 = *reinterpret_cast<const short8*>(Y1 + (size_t)r2 * HID + c8);
        short8 v3 = *reinterpret_cast<const short8*>(Y1 + (size_t)r3 * HID + c8);
#pragma unroll
        for (int j = 0; j < 8; ++j)
            a[j] += (b2f((unsigned short)v0[j]) + b2f((unsigned short)v1[j]))
                  + (b2f((unsigned short)v2[j]) + b2f((unsigned short)v3[j]));
    }
    for (; i < e; ++i) {
        int r0 = list[i];
        short8 v0 = *reinterpret_cast<const short8*>(Y1 + (size_t)r0 * HID + c8);
#pragma unroll
        for (int j = 0; j < 8; ++j) a[j] += b2f((unsigned short)v0[j]);
    }
    const float sc = 1.0f / (float)max(e - s, 1);
    float4 cv0 = *reinterpret_cast<const float4*>(c1 + c8);
    float4 cv1 = *reinterpret_cast<const float4*>(c1 + c8 + 4);
    float r[8];
    r[0] = fmaxf(a[0] * sc + cv0.x, 0.f); r[1] = fmaxf(a[1] * sc + cv0.y, 0.f);
    r[2] = fmaxf(a[2] * sc + cv0.z, 0.f); r[3] = fmaxf(a[3] * sc + cv0.w, 0.f);
    r[4] = fmaxf(a[4] * sc + cv1.x, 0.f); r[5] = fmaxf(a[5] * sc + cv1.y, 0.f);
    r[6] = fmaxf(a[6] * sc + cv1.z, 0.f); r[7] = fmaxf(a[7] * sc + cv1.w, 0.f);
    uint4 o;
    o.x = pk2(r[0], r[1]); o.y = pk2(r[2], r[3]);
    o.z = pk2(r[4], r[5]); o.w = pk2(r[6], r[7]);
    *reinterpret_cast<uint4*>(user_x + (size_t)node * HID + c8) = o;
}

// ================= swapped-operand MFMA GEMM, W staged in LDS =================
template<int K, int NO, bool AVEC, bool RELU, bool F32OUT>
__global__ __launch_bounds__(256) void k_mf2(const unsigned short* __restrict__ X,
                                             const unsigned short* __restrict__ W,
                                             const float* __restrict__ vec,
                                             void* __restrict__ Yv, int M) {
    constexpr int KT = K / 32;
    constexpr int CG = NO / 16;
    constexpr int WB = NO * K * 2;
    constexpr int RB = K * 2;
    __shared__ __align__(16) char lds[WB];
    const int tid = threadIdx.x;
    const int lane = tid & 63;
    const int wv = tid >> 6;
    const int rbase = blockIdx.x * 128 + wv * 32;
    const int lr = lane & 15;
    const int kg = lane >> 4;

#pragma unroll
    for (int i = 0; i < WB / 16 / 256; ++i) {
        int idx = tid + i * 256;
        int row = idx / (RB / 16);
        int bc = (idx % (RB / 16)) * 16;
        *reinterpret_cast<uint4*>(lds + wswz(row, bc, RB)) =
            *reinterpret_cast<const uint4*>((const char*)W + idx * 16);
    }

    short8 xb[2][KT];
#pragma unroll
    for (int t = 0; t < 2; ++t) {
        int row = min(rbase + t * 16 + lr, M - 1);
#pragma unroll
        for (int kt = 0; kt < KT; ++kt)
            xb[t][kt] = *reinterpret_cast<const short8*>(
                X + (size_t)row * K + kt * 32 + kg * 8);
    }
    __syncthreads();

    f32x4 acc[2][CG];
#pragma unroll
    for (int t = 0; t < 2; ++t)
#pragma unroll
        for (int c = 0; c < CG; ++c) acc[t][c] = (f32x4){0.f, 0.f, 0.f, 0.f};

#pragma unroll
    for (int cg = 0; cg < CG; ++cg) {
        short8 wf[KT];
#pragma unroll
        for (int kt = 0; kt < KT; ++kt)
            wf[kt] = *reinterpret_cast<const short8*>(
                lds + wswz(cg * 16 + lr, kt * 64 + kg * 16, RB));
#pragma unroll
        for (int kt = 0; kt < KT; ++kt)
#pragma unroll
            for (int t = 0; t < 2; ++t)
                acc[t][cg] = __builtin_amdgcn_mfma_f32_16x16x32_bf16(
                    wf[kt], xb[t][kt], acc[t][cg], 0, 0, 0);
    }

#pragma unroll
    for (int t = 0; t < 2; ++t) {
        const int u = rbase + t * 16 + lr;
        if (u >= M) continue;
#pragma unroll
        for (int cg = 0; cg < CG; ++cg) {
            const int h0 = cg * 16 + kg * 4;
            float v[4];
#pragma unroll
            for (int r = 0; r < 4; ++r) v[r] = acc[t][cg][r];
            if (AVEC) {
                float4 vv = *reinterpret_cast<const float4*>(vec + h0);
                v[0] += vv.x; v[1] += vv.y; v[2] += vv.z; v[3] += vv.w;
            }
            if (RELU)
#pragma unroll
                for (int r = 0; r < 4; ++r) v[r] = fmaxf(v[r], 0.f);
            if (F32OUT) {
                float4 o = make_float4(v[0], v[1], v[2], v[3]);
                *reinterpret_cast<float4*>((float*)Yv + (size_t)u * NO + h0) = o;
            } else {
                uint2 o = make_uint2(pk2(v[0], v[1]), pk2(v[2], v[3]));
                *reinterpret_cast<uint2*>((unsigned short*)Yv + (size_t)u * NO + h0) = o;
            }
        }
    }
}

// ================= fused user chain (slim: W3l pushed through mean as S3 carry) =================
// Z = relu(S3 + user_x@W3r^T + b3); out = Z@Wlin1^T + blin1
__global__ __launch_bounds__(256) void k_fused_u(
        const unsigned short* __restrict__ S3, const unsigned short* __restrict__ user_x,
        const unsigned short* __restrict__ W3r, const float* __restrict__ b3,
        const unsigned short* __restrict__ Wl1, const float* __restrict__ bl1,
        float* __restrict__ out, int M) {
    __shared__ __align__(16) char lds[49152];   // [0,32K) W3r -> Z; [32K,48K) Wl1 (upfront)
    const int tid = threadIdx.x;
    const int lane = tid & 63;
    const int wv = tid >> 6;
    const int rbase = blockIdx.x * 128 + wv * 32;
    const int lr = lane & 15;
    const int kg = lane >> 4;

#pragma unroll
    for (int i = 0; i < 8; ++i) {
        int idx = tid + i * 256;
        int row = idx >> 4, bc = (idx & 15) << 4;
        *reinterpret_cast<uint4*>(lds + wswz(row, bc, 256)) =
            *reinterpret_cast<const uint4*>((const char*)W3r + idx * 16);
    }
#pragma unroll
    for (int i = 0; i < 4; ++i) {
        int idx = tid + i * 256;
        int row = idx >> 4, bc = (idx & 15) << 4;
        *reinterpret_cast<uint4*>(lds + 32768 + wswz(row, bc, 256)) =
            *reinterpret_cast<const uint4*>((const char*)Wl1 + idx * 16);
    }

    short8 xc[2][4];
#pragma unroll
    for (int t = 0; t < 2; ++t) {
        int row = min(rbase + t * 16 + lr, M - 1);
#pragma unroll
        for (int kt = 0; kt < 4; ++kt)
            xc[t][kt] = *reinterpret_cast<const short8*>(
                user_x + (size_t)row * HID + kt * 32 + kg * 8);
    }
    __syncthreads();

    f32x4 acc[2][8];
#pragma unroll
    for (int t = 0; t < 2; ++t)
#pragma unroll
        for (int c = 0; c < 8; ++c) acc[t][c] = (f32x4){0.f, 0.f, 0.f, 0.f};

#pragma unroll
    for (int cg = 0; cg < 8; ++cg) {
        short8 wr[4];
#pragma unroll
        for (int kt = 0; kt < 4; ++kt)
            wr[kt] = *reinterpret_cast<const short8*>(
                lds + wswz(cg * 16 + lr, kt * 64 + kg * 16, 256));
#pragma unroll
        for (int kt = 0; kt < 4; ++kt)
#pragma unroll
            for (int t = 0; t < 2; ++t)
                acc[t][cg] = __builtin_amdgcn_mfma_f32_16x16x32_bf16(
                    wr[kt], xc[t][kt], acc[t][cg], 0, 0, 0);
    }
    __syncthreads();   // W3r reads done -> Z may overwrite

    // epilogue: Z = relu(acc + S3 + b3) -> swizzled LDS
#pragma unroll
    for (int t = 0; t < 2; ++t) {
        const int ul = wv * 32 + t * 16 + lr;
        const int u = min(rbase + t * 16 + lr, M - 1);
#pragma unroll
        for (int cg = 0; cg < 8; ++cg) {
            const int h0 = cg * 16 + kg * 4;
            uint2 s3 = *reinterpret_cast<const uint2*>(S3 + (size_t)u * HID + h0);
            float4 vv = *reinterpret_cast<const float4*>(b3 + h0);
            float v0 = fmaxf(acc[t][cg][0] + b2f((unsigned short)(s3.x & 0xffff)) + vv.x, 0.f);
            float v1 = fmaxf(acc[t][cg][1] + b2f((unsigned short)(s3.x >> 16)) + vv.y, 0.f);
            float v2 = fmaxf(acc[t][cg][2] + b2f((unsigned short)(s3.y & 0xffff)) + vv.z, 0.f);
            float v3 = fmaxf(acc[t][cg][3] + b2f((unsigned short)(s3.y >> 16)) + vv.w, 0.f);
            uint2 pk = make_uint2(pk2(v0, v1), pk2(v2, v3));
            *reinterpret_cast<uint2*>(lds + wswz(ul, h0 * 2, 256)) = pk;
        }
    }
    __syncthreads();

    // GEMM2: out = Z @ Wlin1^T + blin1
    short8 zb[2][4];
#pragma unroll
    for (int t = 0; t < 2; ++t) {
        const int ul = wv * 32 + t * 16 + lr;
#pragma unroll
        for (int kt = 0; kt < 4; ++kt)
            zb[t][kt] = *reinterpret_cast<const short8*>(
                lds + wswz(ul, kt * 64 + kg * 16, 256));
    }
    f32x4 a2[2][4];
#pragma unroll
    for (int t = 0; t < 2; ++t)
#pragma unroll
        for (int c = 0; c < 4; ++c) a2[t][c] = (f32x4){0.f, 0.f, 0.f, 0.f};
#pragma unroll
    for (int cg = 0; cg < 4; ++cg) {
        short8 wf[4];
#pragma unroll
        for (int kt = 0; kt < 4; ++kt)
            wf[kt] = *reinterpret_cast<const short8*>(
                lds + 32768 + wswz(cg * 16 + lr, kt * 64 + kg * 16, 256));
#pragma unroll
        for (int kt = 0; kt < 4; ++kt)
#pragma unroll
            for (int t = 0; t < 2; ++t)
                a2[t][cg] = __builtin_amdgcn_mfma_f32_16x16x32_bf16(
                    wf[kt], zb[t][kt], a2[t][cg], 0, 0, 0);
    }
#pragma unroll
    for (int t = 0; t < 2; ++t) {
        const int u = rbase + t * 16 + lr;
        if (u >= M) continue;
#pragma unroll
        for (int cg = 0; cg < 4; ++cg) {
            const int o0 = cg * 16 + kg * 4;
            float4 bb = *reinterpret_cast<const float4*>(bl1 + o0);
            float4 o = make_float4(a2[t][cg][0] + bb.x, a2[t][cg][1] + bb.y,
                                   a2[t][cg][2] + bb.z, a2[t][cg][3] + bb.w);
            *reinterpret_cast<float4*>(out + (size_t)u * OUTD + o0) = o;
        }
    }
}

// ================= fused movie chain + Y3 projection =================
__global__ __launch_bounds__(256) void k_fused_m(
        const unsigned short* __restrict__ mean2, const unsigned short* __restrict__ mxb,
        const unsigned short* __restrict__ W2l, const unsigned short* __restrict__ W2r,
        const float* __restrict__ b2, unsigned short* __restrict__ movie_z,
        const unsigned short* __restrict__ Wl2, const float* __restrict__ bl2,
        const unsigned short* __restrict__ W3l, unsigned short* __restrict__ Y3,
        float* __restrict__ out, int M) {
    __shared__ __align__(16) char lds[65536];
    // [0,32K) W2l -> Z; [32K,48K) W2r -> W3l(lo); [48K,64K) Wl2 -> W3l(hi)
    const int tid = threadIdx.x;
    const int lane = tid & 63;
    const int wv = tid >> 6;
    const int rbase = blockIdx.x * 128 + wv * 32;
    const int lr = lane & 15;
    const int kg = lane >> 4;

#pragma unroll
    for (int i = 0; i < 8; ++i) {
        int idx = tid + i * 256;
        int row = idx >> 4, bc = (idx & 15) << 4;
        *reinterpret_cast<uint4*>(lds + wswz(row, bc, 256)) =
            *reinterpret_cast<const uint4*>((const char*)W2l + idx * 16);
    }
#pragma unroll
    for (int i = 0; i < 4; ++i) {
        int idx = tid + i * 256;
        int row = idx >> 3, bc = (idx & 7) << 4;
        *reinterpret_cast<uint4*>(lds + 32768 + wswz(row, bc, 128)) =
            *reinterpret_cast<const uint4*>((const char*)W2r + idx * 16);
        int row2 = idx >> 4, bc2 = (idx & 15) << 4;
        *reinterpret_cast<uint4*>(lds + 49152 + wswz(row2, bc2, 256)) =
            *reinterpret_cast<const uint4*>((const char*)Wl2 + idx * 16);
    }

    short8 xa[2][4], xc[2][2];
#pragma unroll
    for (int t = 0; t < 2; ++t) {
        int row = min(rbase + t * 16 + lr, M - 1);
#pragma unroll
        for (int kt = 0; kt < 4; ++kt)
            xa[t][kt] = *reinterpret_cast<const short8*>(
                mean2 + (size_t)row * HID + kt * 32 + kg * 8);
#pragma unroll
        for (int kt = 0; kt < 2; ++kt)
            xc[t][kt] = *reinterpret_cast<const short8*>(
                mxb + (size_t)row * FEAT + kt * 32 + kg * 8);
    }
    __syncthreads();

    f32x4 acc[2][8];
#pragma unroll
    for (int t = 0; t < 2; ++t)
#pragma unroll
        for (int c = 0; c < 8; ++c) acc[t][c] = (f32x4){0.f, 0.f, 0.f, 0.f};

#pragma unroll
    for (int cg = 0; cg < 8; ++cg) {
        short8 wl[4], wr[2];
#pragma unroll
        for (int kt = 0; kt < 4; ++kt)
            wl[kt] = *reinterpret_cast<const short8*>(
                lds + wswz(cg * 16 + lr, kt * 64 + kg * 16, 256));
#pragma unroll
        for (int kt = 0; kt < 2; ++kt)
            wr[kt] = *reinterpret_cast<const short8*>(
                lds + 32768 + wswz(cg * 16 + lr, kt * 64 + kg * 16, 128));
#pragma unroll
        for (int kt = 0; kt < 4; ++kt)
#pragma unroll
            for (int t = 0; t < 2; ++t)
                acc[t][cg] = __builtin_amdgcn_mfma_f32_16x16x32_bf16(
                    wl[kt], xa[t][kt], acc[t][cg], 0, 0, 0);
#pragma unroll
        for (int kt = 0; kt < 2; ++kt)
#pragma unroll
            for (int t = 0; t < 2; ++t)
                acc[t][cg] = __builtin_amdgcn_mfma_f32_16x16x32_bf16(
                    wr[kt], xc[t][kt], acc[t][cg], 0, 0, 0);
    }
    __syncthreads();   // W2l reads done -> Z may overwrite [0,32K)

    // epilogue 1: relu(acc + b2) -> Z (LDS) + global movie_z
#pragma unroll
    for (int t = 0; t < 2; ++t) {
        const int ul = wv * 32 + t * 16 + lr;
        const int u = rbase + t * 16 + lr;
#pragma unroll
        for (int cg = 0; cg < 8; ++cg) {
            const int h0 = cg * 16 + kg * 4;
            float4 vv = *reinterpret_cast<const float4*>(b2 + h0);
            float v0 = fmaxf(acc[t][cg][0] + vv.x, 0.f);
            float v1 = fmaxf(acc[t][cg][1] + vv.y, 0.f);
            float v2 = fmaxf(acc[t][cg][2] + vv.z, 0.f);
            float v3 = fmaxf(acc[t][cg][3] + vv.w, 0.f);
            uint2 pk = make_uint2(pk2(v0, v1), pk2(v2, v3));
            *reinterpret_cast<uint2*>(lds + wswz(ul, h0 * 2, 256)) = pk;
            if (u < M)
                *reinterpret_cast<uint2*>(movie_z + (size_t)u * HID + h0) = pk;
        }
    }
    __syncthreads();

    // GEMM2: out = Z @ Wlin2^T + blin2
    short8 zb[2][4];
#pragma unroll
    for (int t = 0; t < 2; ++t) {
        const int ul = wv * 32 + t * 16 + lr;
#pragma unroll
        for (int kt = 0; kt < 4; ++kt)
            zb[t][kt] = *reinterpret_cast<const short8*>(
                lds + wswz(ul, kt * 64 + kg * 16, 256));
    }
    f32x4 a2[2][4];
#pragma unroll
    for (int t = 0; t < 2; ++t)
#pragma unroll
        for (int c = 0; c < 4; ++c) a2[t][c] = (f32x4){0.f, 0.f, 0.f, 0.f};
#pragma unroll
    for (int cg = 0; cg < 4; ++cg) {
        short8 wf[4];
#pragma unroll
        for (int kt = 0; kt < 4; ++kt)
            wf[kt] = *reinterpret_cast<const short8*>(
                lds + 49152 + wswz(cg * 16 + lr, kt * 64 + kg * 16, 256));
#pragma unroll
        for (int kt = 0; kt < 4; ++kt)
#pragma unroll
            for (int t = 0; t < 2; ++t)
                a2[t][cg] = __builtin_amdgcn_mfma_f32_16x16x32_bf16(
                    wf[kt], zb[t][kt], a2[t][cg], 0, 0, 0);
    }
#pragma unroll
    for (int t = 0; t < 2; ++t) {
        const int u = rbase + t * 16 + lr;
        if (u >= M) continue;
#pragma unroll
        for (int cg = 0; cg < 4; ++cg) {
            const int o0 = cg * 16 + kg * 4;
            float4 bb = *reinterpret_cast<const float4*>(bl2 + o0);
            float4 o = make_float4(a2[t][cg][0] + bb.x, a2[t][cg][1] + bb.y,
                                   a2[t][cg][2] + bb.z, a2[t][cg][3] + bb.w);
            *reinterpret_cast<float4*>(out + (size_t)u * OUTD + o0) = o;
        }
    }
    __syncthreads();   // Wl2 + W2r reads done -> W3l may overwrite [32K,64K)

    // stage W3l (32KB, 256B rows) at [32K,64K)
#pragma unroll
    for (int i = 0; i < 8; ++i) {
        int idx = tid + i * 256;
        int row = idx >> 4, bc = (idx & 15) << 4;
        *reinterpret_cast<uint4*>(lds + 32768 + wswz(row, bc, 256)) =
            *reinterpret_cast<const uint4*>((const char*)W3l + idx * 16);
    }
    __syncthreads();

    // GEMM3: Y3 = Z @ W3l^T
    f32x4 a3[2][8];
#pragma unroll
    for (int t = 0; t < 2; ++t)
#pragma unroll
        for (int c = 0; c < 8; ++c) a3[t][c] = (f32x4){0.f, 0.f, 0.f, 0.f};
#pragma unroll
    for (int cg = 0; cg < 8; ++cg) {
        short8 wf[4];
#pragma unroll
        for (int kt = 0; kt < 4; ++kt)
            wf[kt] = *reinterpret_cast<const short8*>(
                lds + 32768 + wswz(cg * 16 + lr, kt * 64 + kg * 16, 256));
#pragma unroll
        for (int kt = 0; kt < 4; ++kt)
#pragma unroll
            for (int t = 0; t < 2; ++t)
                a3[t][cg] = __builtin_amdgcn_mfma_f32_16x16x32_bf16(
                    wf[kt], zb[t][kt], a3[t][cg], 0, 0, 0);
    }
#pragma unroll
    for (int t = 0; t < 2; ++t) {
        const int u = rbase + t * 16 + lr;
        if (u >= M) continue;
#pragma unroll
        for (int cg = 0; cg < 8; ++cg) {
            const int h0 = cg * 16 + kg * 4;
            uint2 pk = make_uint2(pk2(a3[t][cg][0], a3[t][cg][1]),
                                  pk2(a3[t][cg][2], a3[t][cg][3]));
            *reinterpret_cast<uint2*>(Y3 + (size_t)u * HID + h0) = pk;
        }
    }
}

extern "C" void kernel_launch(void* const* d_in, const int* in_sizes, int n_in,
                              void* d_out, int out_size, void* d_ws, size_t ws_size,
                              hipStream_t stream) {
    const float* movie_x  = (const float*)d_in[0];
    const int*   user_idx = (const int*)d_in[1];
    const int*   movie_idx= (const int*)d_in[2];
    const int*   tuples   = (const int*)d_in[3];
    const float* user_emb = (const float*)d_in[4];
    const float* W1l = (const float*)d_in[5];
    const float* b1  = (const float*)d_in[6];
    const float* W1r = (const float*)d_in[7];
    const float* W2l = (const float*)d_in[8];
    const float* b2  = (const float*)d_in[9];
    const float* W2r = (const float*)d_in[10];
    const float* W3l = (const float*)d_in[11];
    const float* b3  = (const float*)d_in[12];
    const float* W3r = (const float*)d_in[13];
    const float* Wlin1 = (const float*)d_in[14];
    const float* blin1 = (const float*)d_in[15];
    const float* Wlin2 = (const float*)d_in[16];
    const float* blin2 = (const float*)d_in[17];

    float* out = (float*)d_out;

    // ---- workspace layout ----
    char* p = (char*)d_ws;
    int* gcur = (int*)p;  p += 360 * 4;
    int* entries = (int*)p; p += (size_t)NBUCK * CAP * 4;
    int2* rp2  = (int2*)p; p += (size_t)NTOT * 8;
    int* list  = (int*)p;  p += (size_t)NBUCK * CAP * 4;
    float* c1  = (float*)p; p += 128 * 4;
    unsigned short* wb = (unsigned short*)p; p += (size_t)CVT_TOT * 2;
    unsigned short* W1l_b  = wb;
    unsigned short* W2l_b  = wb + 8192;
    unsigned short* W2r_b  = wb + 24576;
    unsigned short* W3l_b  = wb + 32768;
    unsigned short* W3r_b  = wb + 49152;
    unsigned short* Wlin1_b= wb + 65536;
    unsigned short* Wlin2_b= wb + 73728;
    unsigned short* mxb    = wb + 81920;                              // [NM][64]
    unsigned short* Y1     = (unsigned short*)p; p += (size_t)NM * HID * 2;
    unsigned short* user_x = (unsigned short*)p; p += (size_t)NU * HID * 2;
    unsigned short* mean2  = (unsigned short*)p; p += (size_t)NM * HID * 2;
    unsigned short* movie_z= (unsigned short*)p; p += (size_t)NM * HID * 2;
    unsigned short* Y3     = (unsigned short*)p; p += (size_t)NM * HID * 2;
    unsigned short* S3     = (unsigned short*)p; p += (size_t)NU * HID * 2;

    // ---- pass 1: partition (fixed-cap buckets) + cvt + idx + c1 ----
    hipMemsetAsync(gcur, 0, NBUCK * sizeof(int), stream);
    k_part_misc<<<NPBLK + CVT_BLKS + IDX_BLKS + 1, 256, 0, stream>>>(
        user_idx, movie_idx, gcur, entries,
        W1l, W2l, W2r, W3l, W3r, Wlin1, Wlin2, movie_x, wb,
        tuples, out + (size_t)(NU + NM) * OUTD, user_emb, W1r, b1, c1);
    // ---- pass 2: per-bucket CSR ----
    k_csr<<<NBUCK, 256, 0, stream>>>(gcur, entries, rp2, list);
    // Y1 = movie_x @ W1l^T (conv1 push-through)
    k_mf2<FEAT, HID, false, false, false><<<(NM + 127) / 128, 256, 0, stream>>>(
        mxb, W1l_b, nullptr, Y1, NM);

    // ---- conv1: gather(Y1) + c1 + relu -> user_x ----
    k_gather_relu<<<(NU + 15) / 16, 256, 0, stream>>>(Y1, rp2, list, c1, user_x, NU);

    // ---- conv2 + lin2 + Y3 projection ----
    k_gather_b<HID><<<(NM + 15) / 16, 256, 0, stream>>>(user_x, rp2, list, mean2, NU, NM);
    k_fused_m<<<(NM + 127) / 128, 256, 0, stream>>>(
        mean2, mxb, W2l_b, W2r_b, b2, movie_z, Wlin2_b, blin2, W3l_b, Y3,
        out + (size_t)NU * OUTD, NM);

    // ---- conv3 + lin1 ----
    k_gather_b<HID><<<(NU + 15) / 16, 256, 0, stream>>>(Y3, rp2, list, S3, 0, NU);
    k_fused_u<<<(NU + 127) / 128, 256, 0, stream>>>(
        S3, user_x, W3r_b, b3, Wlin1_b, blin1, out, NU);
}